// Round 9
// baseline (465.476 us; speedup 1.0000x reference)
//
#include <hip/hip_runtime.h>

// MetaTransformer collapse: per layer,
//   G[b]  = Zx[b,:2047]^T Zx[b,:2047]   (256x256, symmetric)   gcol = Zx^T zlab
//   V     = G Pcat^T  (256 x 2048 stacked heads);  M = Qcat2 (Vt3)^T  (K=2048)
//   mcol  = (1/N) * Qcat2-GEMV(gcol)
//   Z[b] += Zx[b] M[b]  (+ label-col GEMV with mcol)
// 64x64-per-wave MFMA tiles, split-K-16 with BF16 partials stored TRANSPOSED
// (contiguous short4 stores; G symmetric so col-major == G; qm operand order
// chosen so transposed store == Mt layout). Linear 16B reduce kernels with
// XCD-aligned b = x&7. 25 dispatches, every grid >= 256 wgs.

#define NL   4
#define NH   8
#define DD   256
#define NCH  257
#define NTOK 2048
#define NVAL 2047
#define NB   8

typedef short  short8v __attribute__((ext_vector_type(8)));
typedef short  short4v __attribute__((ext_vector_type(4)));
typedef float  f32x4   __attribute__((ext_vector_type(4)));

__device__ __forceinline__ unsigned short f2b(float x) {
  union { float f; unsigned u; } v; v.f = x;
  unsigned u = v.u + 0x7fffu + ((v.u >> 16) & 1u);
  return (unsigned short)(u >> 16);
}
__device__ __forceinline__ float b2f(short s) {
  union { unsigned u; float f; } v; v.u = ((unsigned)(unsigned short)s) << 16;
  return v.f;
}

// ---- MFMA tile: one wave computes 64x64 (4x4 fragments), K in [k0,k1).
__device__ __forceinline__ void mm64(const short* A, const short* B, int lda, int ldb,
                                     int ar, int bc, int k0, int k1, int lane,
                                     f32x4 (&acc)[4][4]) {
  #pragma unroll 2
  for (int kk = k0; kk < k1; kk += 32) {
    const int kc = kk + ((lane >> 4) << 3);
    short8v av[4], bv[4];
    #pragma unroll
    for (int f = 0; f < 4; ++f)
      av[f] = *(const short8v*)(A + (size_t)(ar + f * 16 + (lane & 15)) * lda + kc);
    #pragma unroll
    for (int g = 0; g < 4; ++g)
      bv[g] = *(const short8v*)(B + (size_t)(bc + g * 16 + (lane & 15)) * ldb + kc);
    #pragma unroll
    for (int f = 0; f < 4; ++f)
      #pragma unroll
      for (int g = 0; g < 4; ++g)
        acc[f][g] = __builtin_amdgcn_mfma_f32_16x16x32_bf16(av[f], bv[g], acc[f][g], 0, 0, 0);
  }
}

// ---- k_init: flat grid 3072.
//   [0,1024)     P cast -> Pbf
//   [1024,2048)  Q permute-cast -> Qcat2[l][k][j*256+t]
//   [2048,3072)  Zin -> Zxbf (natural bf16), Zxt (transposed, m=2047 zeroed), zlab
__global__ __launch_bounds__(256) void k_init(const float* __restrict__ Zin,
                                              const float* __restrict__ ap,
                                              short* __restrict__ Pbf, short* __restrict__ Qcat2,
                                              short* __restrict__ Zxbf, short* __restrict__ Zxt,
                                              float* __restrict__ zlab) {
  __shared__ float lds[64][65];
  const int bx = blockIdx.x, tid = threadIdx.x;
  if (bx < 1024) {
    const f32x4* src = (const f32x4*)ap;
    int q0 = (bx * 256 + tid) * 2;
    #pragma unroll
    for (int u = 0; u < 2; ++u) {
      int q = q0 + u, lj = q >> 14, rc4 = q & 16383;
      f32x4 v = src[(size_t)(lj * 2) * 16384 + rc4];
      short4v o;
      #pragma unroll
      for (int i = 0; i < 4; ++i) o[i] = (short)f2b(v[i]);
      ((short4v*)Pbf)[(size_t)lj * 16384 + rc4] = o;
    }
    return;
  }
  if (bx < 2048) {
    int idx = bx - 1024;
    int l = idx >> 8, k = idx & 255;
    int j = tid >> 5, t0 = (tid & 31) * 8;
    const float* s = ap + (size_t)((l * 8 + j) * 2 + 1) * 65536 + (size_t)k * 256 + t0;
    f32x4 a = *(const f32x4*)s, bq = *(const f32x4*)(s + 4);
    short8v o;
    #pragma unroll
    for (int i = 0; i < 4; ++i) { o[i] = (short)f2b(a[i]); o[4 + i] = (short)f2b(bq[i]); }
    *(short8v*)(Qcat2 + (size_t)(l * 256 + k) * 2048 + j * 256 + t0) = o;
    return;
  }
  int tb = bx - 2048;
  int x = tb & 3, y = (tb >> 2) & 31, b = tb >> 7;
  int k0 = x * 64, m0 = y * 64;
  int c = tid & 63, r = tid >> 6;
  #pragma unroll
  for (int i = 0; i < 16; ++i) {
    int mrow = r + i * 4, m = m0 + mrow;
    float v = Zin[((size_t)b * NTOK + m) * NCH + k0 + c];
    lds[mrow][c] = v;
    Zxbf[((size_t)b * NTOK + m) * DD + k0 + c] = (short)f2b(v);
  }
  if (x == 0 && tid < 64) {
    int m = m0 + tid;
    zlab[b * NTOK + m] = (m == NVAL) ? 0.f : Zin[((size_t)b * NTOK + m) * NCH + DD];
  }
  __syncthreads();
  #pragma unroll
  for (int i = 0; i < 16; ++i) {
    int krow = r + i * 4;
    float v = lds[c][krow];
    if (m0 + c == NVAL) v = 0.f;
    Zxt[((size_t)b * DD + k0 + krow) * NTOK + m0 + c] = (short)f2b(v);
  }
}

// ---- k_gram: grid 576. x<512: b=x&7, tile=(x>>3)&3 (128x128 quadrant), seg=x>>5
//      (K=128 window) -> bf16 partials stored TRANSPOSED (col-major; G symmetric).
//      x>=512: gcol partials over 256-m segment via Zxbf.
__global__ __launch_bounds__(256) void k_gram(const short* __restrict__ Zxt,
                                              const short* __restrict__ Zxbf,
                                              const float* __restrict__ zlab,
                                              short* __restrict__ Gacc,
                                              float* __restrict__ gcolacc) {
  __shared__ float zl[256];
  const int x = blockIdx.x, tid = threadIdx.x;
  if (x >= 512) {
    const int idx = x - 512, b = idx & 7, seg = idx >> 3;
    zl[tid] = zlab[b * NTOK + seg * 256 + tid];
    __syncthreads();
    const short* base = Zxbf + ((size_t)b * NTOK + seg * 256) * DD + tid;
    float s = 0.f;
    #pragma unroll 8
    for (int m = 0; m < 256; ++m) s += b2f(base[(size_t)m * DD]) * zl[m];
    gcolacc[(seg * 8 + b) * 256 + tid] = s;
    return;
  }
  const int lane = tid & 63, wid = tid >> 6;
  const int b = x & 7, t = (x >> 3) & 3, seg = x >> 5;
  const int r0 = (t >> 1) * 128, c0 = (t & 1) * 128;
  const int ar = r0 + (wid >> 1) * 64, bc = c0 + (wid & 1) * 64;
  const short* A = Zxt + (size_t)b * DD * NTOK;
  f32x4 acc[4][4];
  #pragma unroll
  for (int f = 0; f < 4; ++f) for (int g = 0; g < 4; ++g) for (int i = 0; i < 4; ++i) acc[f][g][i] = 0.f;
  mm64(A, A, NTOK, NTOK, ar, bc, seg * 128, seg * 128 + 128, lane, acc);
  short* out = Gacc + (size_t)(seg * 8 + b) * 65536;
  #pragma unroll
  for (int f = 0; f < 4; ++f) {
    const int rb = ar + f * 16 + ((lane >> 4) << 2);
    #pragma unroll
    for (int g = 0; g < 4; ++g) {
      const int col = bc + g * 16 + (lane & 15);
      short4v p;
      #pragma unroll
      for (int i = 0; i < 4; ++i) p[i] = (short)f2b(acc[f][g][i]);
      *(short4v*)(out + (size_t)col * 256 + rb) = p;   // transposed, contiguous 8B
    }
  }
}

// ---- k_gred: grid 264. x<256: b=x&7, linear 16-seg bf16 reduce -> Gbf (16B ld/st).
//      x>=256: gcol 8-seg reduce.
__global__ __launch_bounds__(256) void k_gred(const short* __restrict__ Gacc,
                                              const float* __restrict__ gcolacc,
                                              short* __restrict__ Gbf, float* __restrict__ gcol) {
  const int x = blockIdx.x, tid = threadIdx.x;
  if (x >= 256) {
    const int b = x - 256;
    float s = 0.f;
    #pragma unroll
    for (int seg = 0; seg < 8; ++seg) s += gcolacc[(seg * 8 + b) * 256 + tid];
    gcol[b * 256 + tid] = s;
    return;
  }
  const int b = x & 7, chunk = x >> 3;
  const int i0 = chunk * 2048 + tid * 8;
  float s[8] = {};
  #pragma unroll
  for (int seg = 0; seg < 16; ++seg) {
    short8v v = *(const short8v*)(Gacc + (size_t)(seg * 8 + b) * 65536 + i0);
    #pragma unroll
    for (int q = 0; q < 8; ++q) s[q] += b2f(v[q]);
  }
  short8v o;
  #pragma unroll
  for (int q = 0; q < 8; ++q) o[q] = (short)f2b(s[q]);
  *(short8v*)(Gbf + (size_t)b * 65536 + i0) = o;
}

// ---- k_pv: grid 264. x<256: b=x&7, t=x>>3: 128t x 128jc tile of V = G Pcat^T;
//      write Vt3[b][c][j*256+t]. x>=256: mcol[k] = invN * sum_jt Qcat2[k][jt]*gcol[t].
__global__ __launch_bounds__(256) void k_pv(const short* __restrict__ Gbf, const short* __restrict__ Pbf,
                                            const short* __restrict__ Qcat2, const float* __restrict__ gcol,
                                            short* __restrict__ Vt3, float* __restrict__ mcol, int layer) {
  __shared__ float gs[256];
  const int x = blockIdx.x, tid = threadIdx.x;
  if (x >= 256) {
    const int b = x - 256;
    gs[tid] = gcol[b * 256 + tid];
    __syncthreads();
    const short* qrow = Qcat2 + (size_t)layer * 524288 + (size_t)tid * 2048;
    float s = 0.f;
    for (int jt = 0; jt < 2048; jt += 8) {
      short8v v = *(const short8v*)(qrow + jt);
      #pragma unroll
      for (int q = 0; q < 8; ++q) s += b2f(v[q]) * gs[(jt + q) & 255];
    }
    mcol[b * 256 + tid] = s * (1.0f / (float)NVAL);
    return;
  }
  const int lane = tid & 63, wid = tid >> 6;
  const int b = x & 7, t = x >> 3;
  const int r0 = (t & 1) * 128, c0 = (t >> 1) * 128;   // r0: t-dim, c0: jc-dim
  const int ar = r0 + (wid >> 1) * 64, bc = c0 + (wid & 1) * 64;
  const short* A = Gbf + (size_t)b * 65536;
  const short* B = Pbf + (size_t)layer * 8 * 65536;
  f32x4 acc[4][4];
  #pragma unroll
  for (int f = 0; f < 4; ++f) for (int g = 0; g < 4; ++g) for (int i = 0; i < 4; ++i) acc[f][g][i] = 0.f;
  mm64(A, B, 256, 256, ar, bc, 0, 256, lane, acc);
  short* out = Vt3 + (size_t)b * 524288;
  #pragma unroll
  for (int f = 0; f < 4; ++f) {
    const int tt0 = ar + f * 16 + ((lane >> 4) << 2);
    #pragma unroll
    for (int g = 0; g < 4; ++g) {
      const int jc = bc + g * 16 + (lane & 15);
      const int j = jc >> 8, c = jc & 255;
      short4v p;
      #pragma unroll
      for (int i = 0; i < 4; ++i) p[i] = (short)f2b(acc[f][g][i]);
      *(short4v*)(out + (size_t)c * 2048 + j * 256 + tt0) = p;
    }
  }
}

// ---- k_qm: grid 512. b=x&7, tile=(x>>3)&3 (128k x 128c of M), seg=x>>5 (K=128 of jt).
//      A'=Qcat2[l] rows k, B'=Vt3[b] rows c -> out[k][c]; bf16 partial stored
//      TRANSPOSED => Macc[seg][b][c*256+k] (contiguous short4, == Mt layout).
__global__ __launch_bounds__(256) void k_qm(const short* __restrict__ Vt3, const short* __restrict__ Qcat2,
                                            short* __restrict__ Macc, int layer) {
  const int x = blockIdx.x, tid = threadIdx.x;
  const int lane = tid & 63, wid = tid >> 6;
  const int b = x & 7, t = (x >> 3) & 3, seg = x >> 5;
  const int r0 = (t >> 1) * 128, c0 = (t & 1) * 128;   // r0: k-dim, c0: c-dim
  const int ar = r0 + (wid >> 1) * 64, bc = c0 + (wid & 1) * 64;
  const short* A = Qcat2 + (size_t)layer * 524288;
  const short* B = Vt3 + (size_t)b * 524288;
  f32x4 acc[4][4];
  #pragma unroll
  for (int f = 0; f < 4; ++f) for (int g = 0; g < 4; ++g) for (int i = 0; i < 4; ++i) acc[f][g][i] = 0.f;
  mm64(A, B, 2048, 2048, ar, bc, seg * 128, seg * 128 + 128, lane, acc);
  short* out = Macc + (size_t)(seg * 8 + b) * 65536;
  #pragma unroll
  for (int f = 0; f < 4; ++f) {
    const int kb = ar + f * 16 + ((lane >> 4) << 2);
    #pragma unroll
    for (int g = 0; g < 4; ++g) {
      const int c = bc + g * 16 + (lane & 15);
      short4v p;
      #pragma unroll
      for (int i = 0; i < 4; ++i) p[i] = (short)f2b(acc[f][g][i]);
      *(short4v*)(out + (size_t)c * 256 + kb) = p;     // [c][k] layout, contiguous 8B
    }
  }
}

// ---- k_mred: grid 256. b=x&7, linear 16-seg bf16 reduce, *invN -> Mt[b][c][k].
__global__ __launch_bounds__(256) void k_mred(const short* __restrict__ Macc, short* __restrict__ Mt) {
  const int x = blockIdx.x, tid = threadIdx.x;
  const int b = x & 7, chunk = x >> 3;
  const int i0 = chunk * 2048 + tid * 8;
  float s[8] = {};
  #pragma unroll
  for (int seg = 0; seg < 16; ++seg) {
    short8v v = *(const short8v*)(Macc + (size_t)(seg * 8 + b) * 65536 + i0);
    #pragma unroll
    for (int q = 0; q < 8; ++q) s[q] += b2f(v[q]);
  }
  const float invN = 1.0f / (float)NVAL;
  short8v o;
  #pragma unroll
  for (int q = 0; q < 8; ++q) o[q] = (short)f2b(s[q] * invN);
  *(short8v*)(Mt + (size_t)b * 65536 + i0) = o;
}

// ---- k_apply: grid 256. b=x&7, t=x>>3: 128n x 128c tile.
//      Z = Zsrc + Zx M (+ label GEMV); fused next-layer staging.
__global__ __launch_bounds__(256) void k_apply(const float* __restrict__ Zsrc, float* __restrict__ Z,
                                               const short* __restrict__ Zxin, const short* __restrict__ Mt,
                                               const float* __restrict__ mcol,
                                               short* __restrict__ Zxout, short* __restrict__ Zxt_out,
                                               float* __restrict__ zlab_out, int wnext) {
  __shared__ short ldsT[128][136];
  const int tid = threadIdx.x, lane = tid & 63, wid = tid >> 6;
  const int wr = wid >> 1, wc = wid & 1;
  const int x = blockIdx.x;
  const int b = x & 7, t = x >> 3;
  const int ar_wg = (t >> 1) * 128, bc_wg = (t & 1) * 128;
  const int ar = ar_wg + wr * 64, bc = bc_wg + wc * 64;
  const short* A = Zxin + (size_t)b * NTOK * DD;
  const short* B = Mt + (size_t)b * 65536;
  const bool gemv = ((t & 1) == 0 && wc == 0);
  f32x4 acc[4][4];
  #pragma unroll
  for (int f = 0; f < 4; ++f) for (int g = 0; g < 4; ++g) for (int i = 0; i < 4; ++i) acc[f][g][i] = 0.f;
  float s[4] = {0.f, 0.f, 0.f, 0.f};
  #pragma unroll 2
  for (int kk = 0; kk < 256; kk += 32) {
    const int kc = kk + ((lane >> 4) << 3);
    short8v av[4], bv[4];
    #pragma unroll
    for (int f = 0; f < 4; ++f)
      av[f] = *(const short8v*)(A + (size_t)(ar + f * 16 + (lane & 15)) * DD + kc);
    #pragma unroll
    for (int g = 0; g < 4; ++g)
      bv[g] = *(const short8v*)(B + (size_t)(bc + g * 16 + (lane & 15)) * 256 + kc);
    if (gemv) {
      const float* mp = mcol + b * 256 + kc;
      f32x4 m0 = *(const f32x4*)mp, m1 = *(const f32x4*)(mp + 4);
      #pragma unroll
      for (int f = 0; f < 4; ++f) {
        #pragma unroll
        for (int q = 0; q < 4; ++q) {
          s[f] += b2f(av[f][q]) * m0[q];
          s[f] += b2f(av[f][4 + q]) * m1[q];
        }
      }
    }
    #pragma unroll
    for (int f = 0; f < 4; ++f)
      #pragma unroll
      for (int g = 0; g < 4; ++g)
        acc[f][g] = __builtin_amdgcn_mfma_f32_16x16x32_bf16(av[f], bv[g], acc[f][g], 0, 0, 0);
  }
  #pragma unroll
  for (int f = 0; f < 4; ++f) {
    const int nb = ar + f * 16 + ((lane >> 4) << 2);
    #pragma unroll
    for (int g = 0; g < 4; ++g) {
      const int c = bc + g * 16 + (lane & 15);
      #pragma unroll
      for (int i = 0; i < 4; ++i) {
        size_t idx = ((size_t)b * NTOK + nb + i) * NCH + c;
        float nv = Zsrc[idx] + acc[f][g][i];
        Z[idx] = nv;
        unsigned short bvv = f2b(nv);
        if (wnext) {
          Zxout[((size_t)b * NTOK + nb + i) * DD + c] = (short)bvv;
          ldsT[c - bc_wg][nb - ar_wg + i] = (nb + i == NVAL) ? (short)0 : (short)bvv;
        }
      }
    }
  }
  if (gemv) {
    #pragma unroll
    for (int f = 0; f < 4; ++f) {
      float tt = s[f];
      tt += __shfl_xor(tt, 16);
      tt += __shfl_xor(tt, 32);
      if ((lane >> 4) == 0) {
        int n = ar + f * 16 + (lane & 15);
        size_t idx = ((size_t)b * NTOK + n) * NCH + DD;
        float nv = Zsrc[idx] + tt;
        Z[idx] = nv;
        if (wnext) zlab_out[b * NTOK + n] = (n == NVAL) ? 0.f : nv;
      }
    }
  }
  if (wnext) {
    __syncthreads();
    const int n0 = (tid & 15) * 8, cr0 = (tid >> 4) * 8;
    #pragma unroll
    for (int r = 0; r < 8; ++r) {
      short8v v = *(const short8v*)&ldsT[cr0 + r][n0];
      *(short8v*)(Zxt_out + ((size_t)b * DD + bc_wg + cr0 + r) * NTOK + ar_wg + n0) = v;
    }
  }
}

// =====================================================================================
extern "C" void kernel_launch(void* const* d_in, const int* in_sizes, int n_in,
                              void* d_out, int out_size, void* d_ws, size_t ws_size,
                              hipStream_t stream) {
  const float* Zin      = (const float*)d_in[0];
  const float* allparam = (const float*)d_in[1];
  float* Z = (float*)d_out;

  // ws layout (bytes)
  const size_t o_zx0  = 0;                         // bf16 [8][2048][256]    8,388,608 (ping)
  const size_t o_zx1  = o_zx0  + 8388608;          // bf16                   8,388,608 (pong)
  const size_t o_zxt  = o_zx1  + 8388608;          // bf16 [8][256][2048]    8,388,608
  const size_t o_acc  = o_zxt  + 8388608;          // bf16 [16][8][256][256] 16,777,216 (Gacc/Macc alias)
  const size_t o_gbf  = o_acc  + 16777216;         // bf16 [8][256][256]     1,048,576
  const size_t o_vt   = o_gbf  + 1048576;          // bf16 [8][256][2048]    8,388,608 (Vt3)
  const size_t o_mt   = o_vt   + 8388608;          // bf16 [8][256][256]     1,048,576
  const size_t o_pbf  = o_mt   + 1048576;          // bf16 [4][8][256][256]  4,194,304
  const size_t o_qc2  = o_pbf  + 4194304;          // bf16 [4][256][2048]    4,194,304 (Qcat2)
  const size_t o_gca  = o_qc2  + 4194304;          // f32  [8][8][256]       65,536 (gcolacc)
  const size_t o_gcol = o_gca  + 65536;            // f32  [8][256]          8,192
  const size_t o_mcol = o_gcol + 8192;             // f32  [8][256]          8,192
  const size_t o_zlab = o_mcol + 8192;             // f32  [8][2048]         65,536
  const size_t NEED   = o_zlab + 65536;
  if (ws_size < NEED) return;                      // harness ws is larger; never hit

  char* wsb = (char*)d_ws;
  short* Zx[2]   = { (short*)(wsb + o_zx0), (short*)(wsb + o_zx1) };
  short* Zxt     = (short*)(wsb + o_zxt);
  short* Acc     = (short*)(wsb + o_acc);
  short* Gbf     = (short*)(wsb + o_gbf);
  short* Vt3     = (short*)(wsb + o_vt);
  short* Mt      = (short*)(wsb + o_mt);
  short* Pbf     = (short*)(wsb + o_pbf);
  short* Qcat2   = (short*)(wsb + o_qc2);
  float* gcolacc = (float*)(wsb + o_gca);
  float* gcol    = (float*)(wsb + o_gcol);
  float* mcol    = (float*)(wsb + o_mcol);
  float* zlab    = (float*)(wsb + o_zlab);

  k_init<<<dim3(3072), dim3(256), 0, stream>>>(Zin, allparam, Pbf, Qcat2, Zx[0], Zxt, zlab);

  for (int layer = 0; layer < NL; ++layer) {
    const int cur = layer & 1;
    const int wnext = (layer < NL - 1) ? 1 : 0;
    const float* Zsrc = (layer == 0) ? Zin : Z;
    k_gram<<<dim3(576), dim3(256), 0, stream>>>(Zxt, Zx[cur], zlab, Acc, gcolacc);
    k_gred<<<dim3(264), dim3(256), 0, stream>>>(Acc, gcolacc, Gbf, gcol);
    k_pv<<<dim3(264), dim3(256), 0, stream>>>(Gbf, Pbf, Qcat2, gcol, Vt3, mcol, layer);
    k_qm<<<dim3(512), dim3(256), 0, stream>>>(Vt3, Qcat2, Acc, layer);
    k_mred<<<dim3(256), dim3(256), 0, stream>>>(Acc, Mt);
    k_apply<<<dim3(256), dim3(256), 0, stream>>>(Zsrc, Z, Zx[cur], Mt, mcol,
                                                 Zx[cur ^ 1], Zxt, zlab, wnext);
  }
}

// Round 10
// 378.131 us; speedup vs baseline: 1.2310x; 1.2310x over previous
//
#include <hip/hip_runtime.h>

// MetaTransformer collapse: per layer,
//   G[b]  = Zx[b,:2047]^T Zx[b,:2047]   (256x256, symmetric)   gcol = Zx^T zlab
//   V     = G Pcat^T  (256 x 2048 stacked heads);  M = Qcat2 (Vt3)^T  (K=2048)
//   mcol  = (1/N) QsumT^T gcol   (QsumT precomputed, coalesced reads)
//   Z[b] += Zx[b] M[b]  (+ label-col GEMV with mcol)
// 64x64-per-wave MFMA tiles, split-K-16 with BF16 partials stored TRANSPOSED
// (contiguous short4 stores; G symmetric so col-major == G; qm operand order
// chosen so transposed store == Mt layout). Linear 16B reduce kernels with
// XCD-aligned b = x&7. 25 dispatches, every grid >= 256 wgs.

#define NL   4
#define NH   8
#define DD   256
#define NCH  257
#define NTOK 2048
#define NVAL 2047
#define NB   8

typedef short  short8v __attribute__((ext_vector_type(8)));
typedef short  short4v __attribute__((ext_vector_type(4)));
typedef float  f32x4   __attribute__((ext_vector_type(4)));

__device__ __forceinline__ unsigned short f2b(float x) {
  union { float f; unsigned u; } v; v.f = x;
  unsigned u = v.u + 0x7fffu + ((v.u >> 16) & 1u);
  return (unsigned short)(u >> 16);
}
__device__ __forceinline__ float b2f(short s) {
  union { unsigned u; float f; } v; v.u = ((unsigned)(unsigned short)s) << 16;
  return v.f;
}

// ---- MFMA tile: one wave computes 64x64 (4x4 fragments), K in [k0,k1).
__device__ __forceinline__ void mm64(const short* A, const short* B, int lda, int ldb,
                                     int ar, int bc, int k0, int k1, int lane,
                                     f32x4 (&acc)[4][4]) {
  #pragma unroll 2
  for (int kk = k0; kk < k1; kk += 32) {
    const int kc = kk + ((lane >> 4) << 3);
    short8v av[4], bv[4];
    #pragma unroll
    for (int f = 0; f < 4; ++f)
      av[f] = *(const short8v*)(A + (size_t)(ar + f * 16 + (lane & 15)) * lda + kc);
    #pragma unroll
    for (int g = 0; g < 4; ++g)
      bv[g] = *(const short8v*)(B + (size_t)(bc + g * 16 + (lane & 15)) * ldb + kc);
    #pragma unroll
    for (int f = 0; f < 4; ++f)
      #pragma unroll
      for (int g = 0; g < 4; ++g)
        acc[f][g] = __builtin_amdgcn_mfma_f32_16x16x32_bf16(av[f], bv[g], acc[f][g], 0, 0, 0);
  }
}

// ---- k_init: flat grid 3136.
//   [0,1024)     P cast -> Pbf
//   [1024,2048)  Q permute-cast -> Qcat2[l][k][j*256+t]
//   [2048,2112)  QsumT[l][t][k] = sum_j Q_j[k][t]  (fp32)
//   [2112,3136)  Zin -> Zxbf (natural bf16), Zxt (transposed, m=2047 zeroed), zlab
__global__ __launch_bounds__(256) void k_init(const float* __restrict__ Zin,
                                              const float* __restrict__ ap,
                                              short* __restrict__ Pbf, short* __restrict__ Qcat2,
                                              float* __restrict__ QsumT,
                                              short* __restrict__ Zxbf, short* __restrict__ Zxt,
                                              float* __restrict__ zlab) {
  __shared__ float lds[64][65];
  const int bx = blockIdx.x, tid = threadIdx.x;
  if (bx < 1024) {
    const f32x4* src = (const f32x4*)ap;
    int q0 = (bx * 256 + tid) * 2;
    #pragma unroll
    for (int u = 0; u < 2; ++u) {
      int q = q0 + u, lj = q >> 14, rc4 = q & 16383;
      f32x4 v = src[(size_t)(lj * 2) * 16384 + rc4];
      short4v o;
      #pragma unroll
      for (int i = 0; i < 4; ++i) o[i] = (short)f2b(v[i]);
      ((short4v*)Pbf)[(size_t)lj * 16384 + rc4] = o;
    }
    return;
  }
  if (bx < 2048) {
    int idx = bx - 1024;
    int l = idx >> 8, k = idx & 255;
    int j = tid >> 5, t0 = (tid & 31) * 8;
    const float* s = ap + (size_t)((l * 8 + j) * 2 + 1) * 65536 + (size_t)k * 256 + t0;
    f32x4 a = *(const f32x4*)s, bq = *(const f32x4*)(s + 4);
    short8v o;
    #pragma unroll
    for (int i = 0; i < 4; ++i) { o[i] = (short)f2b(a[i]); o[4 + i] = (short)f2b(bq[i]); }
    *(short8v*)(Qcat2 + (size_t)(l * 256 + k) * 2048 + j * 256 + t0) = o;
    return;
  }
  if (bx < 2112) {
    int qb = bx - 2048;
    int l = qb >> 4, xx = qb & 15;
    int k0 = (xx >> 2) * 64, t0 = (xx & 3) * 64;
    int c = tid & 63, r = tid >> 6;
    #pragma unroll
    for (int i = 0; i < 16; ++i) {
      int k = r + i * 4;
      float s = 0.f;
      #pragma unroll
      for (int j = 0; j < 8; ++j)
        s += ap[(size_t)((l * 8 + j) * 2 + 1) * 65536 + (size_t)(k0 + k) * 256 + (t0 + c)];
      lds[k][c] = s;
    }
    __syncthreads();
    #pragma unroll
    for (int i = 0; i < 16; ++i) {
      int tl = r + i * 4;
      QsumT[(size_t)l * 65536 + (size_t)(t0 + tl) * 256 + (k0 + c)] = lds[c][tl];
    }
    return;
  }
  int tb = bx - 2112;
  int x = tb & 3, y = (tb >> 2) & 31, b = tb >> 7;
  int k0 = x * 64, m0 = y * 64;
  int c = tid & 63, r = tid >> 6;
  #pragma unroll
  for (int i = 0; i < 16; ++i) {
    int mrow = r + i * 4, m = m0 + mrow;
    float v = Zin[((size_t)b * NTOK + m) * NCH + k0 + c];
    lds[mrow][c] = v;
    Zxbf[((size_t)b * NTOK + m) * DD + k0 + c] = (short)f2b(v);
  }
  if (x == 0 && tid < 64) {
    int m = m0 + tid;
    zlab[b * NTOK + m] = (m == NVAL) ? 0.f : Zin[((size_t)b * NTOK + m) * NCH + DD];
  }
  __syncthreads();
  #pragma unroll
  for (int i = 0; i < 16; ++i) {
    int krow = r + i * 4;
    float v = lds[c][krow];
    if (m0 + c == NVAL) v = 0.f;
    Zxt[((size_t)b * DD + k0 + krow) * NTOK + m0 + c] = (short)f2b(v);
  }
}

// ---- k_gram: grid 576. x<512: b=x&7, tile=(x>>3)&3 (128x128 quadrant), seg=x>>5
//      (K=128 window) -> bf16 partials stored TRANSPOSED (col-major; G symmetric).
//      x>=512: gcol partials over 256-m segment via Zxbf.
__global__ __launch_bounds__(256) void k_gram(const short* __restrict__ Zxt,
                                              const short* __restrict__ Zxbf,
                                              const float* __restrict__ zlab,
                                              short* __restrict__ Gacc,
                                              float* __restrict__ gcolacc) {
  __shared__ float zl[256];
  const int x = blockIdx.x, tid = threadIdx.x;
  if (x >= 512) {
    const int idx = x - 512, b = idx & 7, seg = idx >> 3;
    zl[tid] = zlab[b * NTOK + seg * 256 + tid];
    __syncthreads();
    const short* base = Zxbf + ((size_t)b * NTOK + seg * 256) * DD + tid;
    float s = 0.f;
    #pragma unroll 8
    for (int m = 0; m < 256; ++m) s += b2f(base[(size_t)m * DD]) * zl[m];
    gcolacc[(seg * 8 + b) * 256 + tid] = s;
    return;
  }
  const int lane = tid & 63, wid = tid >> 6;
  const int b = x & 7, t = (x >> 3) & 3, seg = x >> 5;
  const int r0 = (t >> 1) * 128, c0 = (t & 1) * 128;
  const int ar = r0 + (wid >> 1) * 64, bc = c0 + (wid & 1) * 64;
  const short* A = Zxt + (size_t)b * DD * NTOK;
  f32x4 acc[4][4];
  #pragma unroll
  for (int f = 0; f < 4; ++f) for (int g = 0; g < 4; ++g) for (int i = 0; i < 4; ++i) acc[f][g][i] = 0.f;
  mm64(A, A, NTOK, NTOK, ar, bc, seg * 128, seg * 128 + 128, lane, acc);
  short* out = Gacc + (size_t)(seg * 8 + b) * 65536;
  #pragma unroll
  for (int f = 0; f < 4; ++f) {
    const int rb = ar + f * 16 + ((lane >> 4) << 2);
    #pragma unroll
    for (int g = 0; g < 4; ++g) {
      const int col = bc + g * 16 + (lane & 15);
      short4v p;
      #pragma unroll
      for (int i = 0; i < 4; ++i) p[i] = (short)f2b(acc[f][g][i]);
      *(short4v*)(out + (size_t)col * 256 + rb) = p;   // transposed, contiguous 8B
    }
  }
}

// ---- k_gred: grid 264. x<256: b=x&7, linear 16-seg bf16 reduce -> Gbf (16B ld/st).
//      x>=256: gcol 8-seg reduce.
__global__ __launch_bounds__(256) void k_gred(const short* __restrict__ Gacc,
                                              const float* __restrict__ gcolacc,
                                              short* __restrict__ Gbf, float* __restrict__ gcol) {
  const int x = blockIdx.x, tid = threadIdx.x;
  if (x >= 256) {
    const int b = x - 256;
    float s = 0.f;
    #pragma unroll
    for (int seg = 0; seg < 8; ++seg) s += gcolacc[(seg * 8 + b) * 256 + tid];
    gcol[b * 256 + tid] = s;
    return;
  }
  const int b = x & 7, chunk = x >> 3;
  const int i0 = chunk * 2048 + tid * 8;
  float s[8] = {};
  #pragma unroll
  for (int seg = 0; seg < 16; ++seg) {
    short8v v = *(const short8v*)(Gacc + (size_t)(seg * 8 + b) * 65536 + i0);
    #pragma unroll
    for (int q = 0; q < 8; ++q) s[q] += b2f(v[q]);
  }
  short8v o;
  #pragma unroll
  for (int q = 0; q < 8; ++q) o[q] = (short)f2b(s[q]);
  *(short8v*)(Gbf + (size_t)b * 65536 + i0) = o;
}

// ---- k_pv: grid 264. x<256: b=x&7, t=x>>3: 128t x 128jc tile of V = G Pcat^T;
//      write Vt3[b][c][j*256+t]. x>=256: mcol = invN * QsumT gcol (coalesced).
__global__ __launch_bounds__(256) void k_pv(const short* __restrict__ Gbf, const short* __restrict__ Pbf,
                                            const float* __restrict__ QsumT, const float* __restrict__ gcol,
                                            short* __restrict__ Vt3, float* __restrict__ mcol, int layer) {
  __shared__ float gs[256];
  const int x = blockIdx.x, tid = threadIdx.x;
  if (x >= 256) {
    const int b = x - 256;
    gs[tid] = gcol[b * 256 + tid];
    __syncthreads();
    float s = 0.f;
    for (int t = 0; t < 256; ++t) s += QsumT[(size_t)layer * 65536 + (size_t)t * 256 + tid] * gs[t];
    mcol[b * 256 + tid] = s * (1.0f / (float)NVAL);
    return;
  }
  const int lane = tid & 63, wid = tid >> 6;
  const int b = x & 7, t = x >> 3;
  const int r0 = (t & 1) * 128, c0 = (t >> 1) * 128;   // r0: t-dim, c0: jc-dim
  const int ar = r0 + (wid >> 1) * 64, bc = c0 + (wid & 1) * 64;
  const short* A = Gbf + (size_t)b * 65536;
  const short* B = Pbf + (size_t)layer * 8 * 65536;
  f32x4 acc[4][4];
  #pragma unroll
  for (int f = 0; f < 4; ++f) for (int g = 0; g < 4; ++g) for (int i = 0; i < 4; ++i) acc[f][g][i] = 0.f;
  mm64(A, B, 256, 256, ar, bc, 0, 256, lane, acc);
  short* out = Vt3 + (size_t)b * 524288;
  #pragma unroll
  for (int f = 0; f < 4; ++f) {
    const int tt0 = ar + f * 16 + ((lane >> 4) << 2);
    #pragma unroll
    for (int g = 0; g < 4; ++g) {
      const int jc = bc + g * 16 + (lane & 15);
      const int j = jc >> 8, c = jc & 255;
      short4v p;
      #pragma unroll
      for (int i = 0; i < 4; ++i) p[i] = (short)f2b(acc[f][g][i]);
      *(short4v*)(out + (size_t)c * 2048 + j * 256 + tt0) = p;
    }
  }
}

// ---- k_qm: grid 512. b=x&7, tile=(x>>3)&3 (128k x 128c of M), seg=x>>5 (K=128 of jt).
//      A'=Qcat2[l] rows k, B'=Vt3[b] rows c -> out[k][c]; bf16 partial stored
//      TRANSPOSED => Macc[seg][b][c*256+k] (contiguous short4, == Mt layout).
__global__ __launch_bounds__(256) void k_qm(const short* __restrict__ Vt3, const short* __restrict__ Qcat2,
                                            short* __restrict__ Macc, int layer) {
  const int x = blockIdx.x, tid = threadIdx.x;
  const int lane = tid & 63, wid = tid >> 6;
  const int b = x & 7, t = (x >> 3) & 3, seg = x >> 5;
  const int r0 = (t >> 1) * 128, c0 = (t & 1) * 128;   // r0: k-dim, c0: c-dim
  const int ar = r0 + (wid >> 1) * 64, bc = c0 + (wid & 1) * 64;
  const short* A = Qcat2 + (size_t)layer * 524288;
  const short* B = Vt3 + (size_t)b * 524288;
  f32x4 acc[4][4];
  #pragma unroll
  for (int f = 0; f < 4; ++f) for (int g = 0; g < 4; ++g) for (int i = 0; i < 4; ++i) acc[f][g][i] = 0.f;
  mm64(A, B, 2048, 2048, ar, bc, seg * 128, seg * 128 + 128, lane, acc);
  short* out = Macc + (size_t)(seg * 8 + b) * 65536;
  #pragma unroll
  for (int f = 0; f < 4; ++f) {
    const int kb = ar + f * 16 + ((lane >> 4) << 2);
    #pragma unroll
    for (int g = 0; g < 4; ++g) {
      const int c = bc + g * 16 + (lane & 15);
      short4v p;
      #pragma unroll
      for (int i = 0; i < 4; ++i) p[i] = (short)f2b(acc[f][g][i]);
      *(short4v*)(out + (size_t)c * 256 + kb) = p;     // [c][k] layout, contiguous 8B
    }
  }
}

// ---- k_mred: grid 256. b=x&7, linear 16-seg bf16 reduce, *invN -> Mt[b][c][k].
__global__ __launch_bounds__(256) void k_mred(const short* __restrict__ Macc, short* __restrict__ Mt) {
  const int x = blockIdx.x, tid = threadIdx.x;
  const int b = x & 7, chunk = x >> 3;
  const int i0 = chunk * 2048 + tid * 8;
  float s[8] = {};
  #pragma unroll
  for (int seg = 0; seg < 16; ++seg) {
    short8v v = *(const short8v*)(Macc + (size_t)(seg * 8 + b) * 65536 + i0);
    #pragma unroll
    for (int q = 0; q < 8; ++q) s[q] += b2f(v[q]);
  }
  const float invN = 1.0f / (float)NVAL;
  short8v o;
  #pragma unroll
  for (int q = 0; q < 8; ++q) o[q] = (short)f2b(s[q] * invN);
  *(short8v*)(Mt + (size_t)b * 65536 + i0) = o;
}

// ---- k_apply: grid 256. b=x&7, t=x>>3: 128n x 128c tile.
//      Z = Zsrc + Zx M (+ label GEMV); fused next-layer staging.
__global__ __launch_bounds__(256) void k_apply(const float* __restrict__ Zsrc, float* __restrict__ Z,
                                               const short* __restrict__ Zxin, const short* __restrict__ Mt,
                                               const float* __restrict__ mcol,
                                               short* __restrict__ Zxout, short* __restrict__ Zxt_out,
                                               float* __restrict__ zlab_out, int wnext) {
  __shared__ short ldsT[128][136];
  const int tid = threadIdx.x, lane = tid & 63, wid = tid >> 6;
  const int wr = wid >> 1, wc = wid & 1;
  const int x = blockIdx.x;
  const int b = x & 7, t = x >> 3;
  const int ar_wg = (t >> 1) * 128, bc_wg = (t & 1) * 128;
  const int ar = ar_wg + wr * 64, bc = bc_wg + wc * 64;
  const short* A = Zxin + (size_t)b * NTOK * DD;
  const short* B = Mt + (size_t)b * 65536;
  const bool gemv = ((t & 1) == 0 && wc == 0);
  f32x4 acc[4][4];
  #pragma unroll
  for (int f = 0; f < 4; ++f) for (int g = 0; g < 4; ++g) for (int i = 0; i < 4; ++i) acc[f][g][i] = 0.f;
  float s[4] = {0.f, 0.f, 0.f, 0.f};
  #pragma unroll 2
  for (int kk = 0; kk < 256; kk += 32) {
    const int kc = kk + ((lane >> 4) << 3);
    short8v av[4], bv[4];
    #pragma unroll
    for (int f = 0; f < 4; ++f)
      av[f] = *(const short8v*)(A + (size_t)(ar + f * 16 + (lane & 15)) * DD + kc);
    #pragma unroll
    for (int g = 0; g < 4; ++g)
      bv[g] = *(const short8v*)(B + (size_t)(bc + g * 16 + (lane & 15)) * 256 + kc);
    if (gemv) {
      const float* mp = mcol + b * 256 + kc;
      f32x4 m0 = *(const f32x4*)mp, m1 = *(const f32x4*)(mp + 4);
      #pragma unroll
      for (int f = 0; f < 4; ++f) {
        #pragma unroll
        for (int q = 0; q < 4; ++q) {
          s[f] += b2f(av[f][q]) * m0[q];
          s[f] += b2f(av[f][4 + q]) * m1[q];
        }
      }
    }
    #pragma unroll
    for (int f = 0; f < 4; ++f)
      #pragma unroll
      for (int g = 0; g < 4; ++g)
        acc[f][g] = __builtin_amdgcn_mfma_f32_16x16x32_bf16(av[f], bv[g], acc[f][g], 0, 0, 0);
  }
  #pragma unroll
  for (int f = 0; f < 4; ++f) {
    const int nb = ar + f * 16 + ((lane >> 4) << 2);
    #pragma unroll
    for (int g = 0; g < 4; ++g) {
      const int c = bc + g * 16 + (lane & 15);
      #pragma unroll
      for (int i = 0; i < 4; ++i) {
        size_t idx = ((size_t)b * NTOK + nb + i) * NCH + c;
        float nv = Zsrc[idx] + acc[f][g][i];
        Z[idx] = nv;
        unsigned short bvv = f2b(nv);
        if (wnext) {
          Zxout[((size_t)b * NTOK + nb + i) * DD + c] = (short)bvv;
          ldsT[c - bc_wg][nb - ar_wg + i] = (nb + i == NVAL) ? (short)0 : (short)bvv;
        }
      }
    }
  }
  if (gemv) {
    #pragma unroll
    for (int f = 0; f < 4; ++f) {
      float tt = s[f];
      tt += __shfl_xor(tt, 16);
      tt += __shfl_xor(tt, 32);
      if ((lane >> 4) == 0) {
        int n = ar + f * 16 + (lane & 15);
        size_t idx = ((size_t)b * NTOK + n) * NCH + DD;
        float nv = Zsrc[idx] + tt;
        Z[idx] = nv;
        if (wnext) zlab_out[b * NTOK + n] = (n == NVAL) ? 0.f : nv;
      }
    }
  }
  if (wnext) {
    __syncthreads();
    const int n0 = (tid & 15) * 8, cr0 = (tid >> 4) * 8;
    #pragma unroll
    for (int r = 0; r < 8; ++r) {
      short8v v = *(const short8v*)&ldsT[cr0 + r][n0];
      *(short8v*)(Zxt_out + ((size_t)b * DD + bc_wg + cr0 + r) * NTOK + ar_wg + n0) = v;
    }
  }
}

// =====================================================================================
extern "C" void kernel_launch(void* const* d_in, const int* in_sizes, int n_in,
                              void* d_out, int out_size, void* d_ws, size_t ws_size,
                              hipStream_t stream) {
  const float* Zin      = (const float*)d_in[0];
  const float* allparam = (const float*)d_in[1];
  float* Z = (float*)d_out;

  // ws layout (bytes)
  const size_t o_zx0  = 0;                         // bf16 [8][2048][256]    8,388,608 (ping)
  const size_t o_zx1  = o_zx0  + 8388608;          // bf16                   8,388,608 (pong)
  const size_t o_zxt  = o_zx1  + 8388608;          // bf16 [8][256][2048]    8,388,608
  const size_t o_acc  = o_zxt  + 8388608;          // bf16 [16][8][256][256] 16,777,216 (Gacc/Macc alias)
  const size_t o_gbf  = o_acc  + 16777216;         // bf16 [8][256][256]     1,048,576
  const size_t o_vt   = o_gbf  + 1048576;          // bf16 [8][256][2048]    8,388,608 (Vt3)
  const size_t o_mt   = o_vt   + 8388608;          // bf16 [8][256][256]     1,048,576
  const size_t o_pbf  = o_mt   + 1048576;          // bf16 [4][8][256][256]  4,194,304
  const size_t o_qc2  = o_pbf  + 4194304;          // bf16 [4][256][2048]    4,194,304 (Qcat2)
  const size_t o_qsum = o_qc2  + 4194304;          // f32  [4][256][256]     1,048,576
  const size_t o_gca  = o_qsum + 1048576;          // f32  [8][8][256]       65,536 (gcolacc)
  const size_t o_gcol = o_gca  + 65536;            // f32  [8][256]          8,192
  const size_t o_mcol = o_gcol + 8192;             // f32  [8][256]          8,192
  const size_t o_zlab = o_mcol + 8192;             // f32  [8][2048]         65,536
  const size_t NEED   = o_zlab + 65536;
  if (ws_size < NEED) return;                      // harness ws is larger; never hit

  char* wsb = (char*)d_ws;
  short* Zx[2]   = { (short*)(wsb + o_zx0), (short*)(wsb + o_zx1) };
  short* Zxt     = (short*)(wsb + o_zxt);
  short* Acc     = (short*)(wsb + o_acc);
  short* Gbf     = (short*)(wsb + o_gbf);
  short* Vt3     = (short*)(wsb + o_vt);
  short* Mt      = (short*)(wsb + o_mt);
  short* Pbf     = (short*)(wsb + o_pbf);
  short* Qcat2   = (short*)(wsb + o_qc2);
  float* QsumT   = (float*)(wsb + o_qsum);
  float* gcolacc = (float*)(wsb + o_gca);
  float* gcol    = (float*)(wsb + o_gcol);
  float* mcol    = (float*)(wsb + o_mcol);
  float* zlab    = (float*)(wsb + o_zlab);

  k_init<<<dim3(3136), dim3(256), 0, stream>>>(Zin, allparam, Pbf, Qcat2, QsumT,
                                               Zx[0], Zxt, zlab);

  for (int layer = 0; layer < NL; ++layer) {
    const int cur = layer & 1;
    const int wnext = (layer < NL - 1) ? 1 : 0;
    const float* Zsrc = (layer == 0) ? Zin : Z;
    k_gram<<<dim3(576), dim3(256), 0, stream>>>(Zxt, Zx[cur], zlab, Acc, gcolacc);
    k_gred<<<dim3(264), dim3(256), 0, stream>>>(Acc, gcolacc, Gbf, gcol);
    k_pv<<<dim3(264), dim3(256), 0, stream>>>(Gbf, Pbf, QsumT, gcol, Vt3, mcol, layer);
    k_qm<<<dim3(512), dim3(256), 0, stream>>>(Vt3, Qcat2, Acc, layer);
    k_mred<<<dim3(256), dim3(256), 0, stream>>>(Acc, Mt);
    k_apply<<<dim3(256), dim3(256), 0, stream>>>(Zsrc, Z, Zx[cur], Mt, mcol,
                                                 Zx[cur ^ 1], Zxt, zlab, wnext);
  }
}

// Round 11
// 358.462 us; speedup vs baseline: 1.2985x; 1.0549x over previous
//
#include <hip/hip_runtime.h>

// MetaTransformer collapse: per layer,
//   G[b]  = Zx[b,:2047]^T Zx[b,:2047]   (256x256, symmetric)   gcol = Zx^T zlab
//   V     = G Pcat^T  (256 x 2048 stacked heads);  M = Qcat2 (Vt3)^T  (K=2048)
//   mcol  = (1/N) QsumT^T gcol
//   Z[b] += Zx[b] M[b]  (+ label-col GEMV with mcol)
// Residual carried in BF16 (Zx ping-pong) + fp32 zlabtrue for the label col;
// fp32 d_out written only by the final layer's apply. 64x64-per-wave MFMA,
// split-K-16 with bf16 transposed partials, XCD-aligned b = x&7 everywhere.
// 25 dispatches, every grid >= 256 wgs.

#define NL   4
#define NH   8
#define DD   256
#define NCH  257
#define NTOK 2048
#define NVAL 2047
#define NB   8

typedef short  short8v __attribute__((ext_vector_type(8)));
typedef short  short4v __attribute__((ext_vector_type(4)));
typedef float  f32x4   __attribute__((ext_vector_type(4)));

__device__ __forceinline__ unsigned short f2b(float x) {
  union { float f; unsigned u; } v; v.f = x;
  unsigned u = v.u + 0x7fffu + ((v.u >> 16) & 1u);
  return (unsigned short)(u >> 16);
}
__device__ __forceinline__ float b2f(short s) {
  union { unsigned u; float f; } v; v.u = ((unsigned)(unsigned short)s) << 16;
  return v.f;
}

// ---- MFMA tile: one wave computes 64x64 (4x4 fragments), K in [k0,k1).
__device__ __forceinline__ void mm64(const short* A, const short* B, int lda, int ldb,
                                     int ar, int bc, int k0, int k1, int lane,
                                     f32x4 (&acc)[4][4]) {
  #pragma unroll 2
  for (int kk = k0; kk < k1; kk += 32) {
    const int kc = kk + ((lane >> 4) << 3);
    short8v av[4], bv[4];
    #pragma unroll
    for (int f = 0; f < 4; ++f)
      av[f] = *(const short8v*)(A + (size_t)(ar + f * 16 + (lane & 15)) * lda + kc);
    #pragma unroll
    for (int g = 0; g < 4; ++g)
      bv[g] = *(const short8v*)(B + (size_t)(bc + g * 16 + (lane & 15)) * ldb + kc);
    #pragma unroll
    for (int f = 0; f < 4; ++f)
      #pragma unroll
      for (int g = 0; g < 4; ++g)
        acc[f][g] = __builtin_amdgcn_mfma_f32_16x16x32_bf16(av[f], bv[g], acc[f][g], 0, 0, 0);
  }
}

// ---- k_init: flat grid 3136.
//   [0,1024)     P cast -> Pbf
//   [1024,2048)  Q permute-cast -> Qcat2[l][k][j*256+t]
//   [2048,2112)  QsumT[l][t][k] = sum_j Q_j[k][t]  (fp32)
//   [2112,3136)  Zin -> Zxbf (natural bf16), Zxt (transposed, m=2047 zeroed),
//                zlab (zeroed @ NVAL) + zlabtrue (exact)
__global__ __launch_bounds__(256) void k_init(const float* __restrict__ Zin,
                                              const float* __restrict__ ap,
                                              short* __restrict__ Pbf, short* __restrict__ Qcat2,
                                              float* __restrict__ QsumT,
                                              short* __restrict__ Zxbf, short* __restrict__ Zxt,
                                              float* __restrict__ zlab, float* __restrict__ zlabtrue) {
  __shared__ float lds[64][65];
  const int bx = blockIdx.x, tid = threadIdx.x;
  if (bx < 1024) {
    const f32x4* src = (const f32x4*)ap;
    int q0 = (bx * 256 + tid) * 2;
    #pragma unroll
    for (int u = 0; u < 2; ++u) {
      int q = q0 + u, lj = q >> 14, rc4 = q & 16383;
      f32x4 v = src[(size_t)(lj * 2) * 16384 + rc4];
      short4v o;
      #pragma unroll
      for (int i = 0; i < 4; ++i) o[i] = (short)f2b(v[i]);
      ((short4v*)Pbf)[(size_t)lj * 16384 + rc4] = o;
    }
    return;
  }
  if (bx < 2048) {
    int idx = bx - 1024;
    int l = idx >> 8, k = idx & 255;
    int j = tid >> 5, t0 = (tid & 31) * 8;
    const float* s = ap + (size_t)((l * 8 + j) * 2 + 1) * 65536 + (size_t)k * 256 + t0;
    f32x4 a = *(const f32x4*)s, bq = *(const f32x4*)(s + 4);
    short8v o;
    #pragma unroll
    for (int i = 0; i < 4; ++i) { o[i] = (short)f2b(a[i]); o[4 + i] = (short)f2b(bq[i]); }
    *(short8v*)(Qcat2 + (size_t)(l * 256 + k) * 2048 + j * 256 + t0) = o;
    return;
  }
  if (bx < 2112) {
    int qb = bx - 2048;
    int l = qb >> 4, xx = qb & 15;
    int k0 = (xx >> 2) * 64, t0 = (xx & 3) * 64;
    int c = tid & 63, r = tid >> 6;
    #pragma unroll
    for (int i = 0; i < 16; ++i) {
      int k = r + i * 4;
      float s = 0.f;
      #pragma unroll
      for (int j = 0; j < 8; ++j)
        s += ap[(size_t)((l * 8 + j) * 2 + 1) * 65536 + (size_t)(k0 + k) * 256 + (t0 + c)];
      lds[k][c] = s;
    }
    __syncthreads();
    #pragma unroll
    for (int i = 0; i < 16; ++i) {
      int tl = r + i * 4;
      QsumT[(size_t)l * 65536 + (size_t)(t0 + tl) * 256 + (k0 + c)] = lds[c][tl];
    }
    return;
  }
  int tb = bx - 2112;
  int x = tb & 3, y = (tb >> 2) & 31, b = tb >> 7;
  int k0 = x * 64, m0 = y * 64;
  int c = tid & 63, r = tid >> 6;
  #pragma unroll
  for (int i = 0; i < 16; ++i) {
    int mrow = r + i * 4, m = m0 + mrow;
    float v = Zin[((size_t)b * NTOK + m) * NCH + k0 + c];
    lds[mrow][c] = v;
    Zxbf[((size_t)b * NTOK + m) * DD + k0 + c] = (short)f2b(v);
  }
  if (x == 0 && tid < 64) {
    int m = m0 + tid;
    float lv = Zin[((size_t)b * NTOK + m) * NCH + DD];
    zlabtrue[b * NTOK + m] = lv;
    zlab[b * NTOK + m] = (m == NVAL) ? 0.f : lv;
  }
  __syncthreads();
  // transposed store: thread -> 4 krows x short4 along m (8B/lane, coalesced)
  const int mt = tid & 15, kg = tid >> 4;
  #pragma unroll
  for (int i = 0; i < 4; ++i) {
    int krow = kg * 4 + i;
    int m4 = mt * 4;
    short4v o;
    #pragma unroll
    for (int q = 0; q < 4; ++q) {
      float v = lds[m4 + q][krow];
      o[q] = (m0 + m4 + q == NVAL) ? (short)0 : (short)f2b(v);
    }
    *(short4v*)(Zxt + ((size_t)b * DD + k0 + krow) * NTOK + m0 + m4) = o;
  }
}

// ---- k_gram: grid 576. x<512: b=x&7, tile=(x>>3)&3 (128x128 quadrant), seg=x>>5
//      (K=128 window) -> bf16 partials stored TRANSPOSED (col-major; G symmetric).
//      x>=512: gcol partials over 256-m segment via Zxbf.
__global__ __launch_bounds__(256) void k_gram(const short* __restrict__ Zxt,
                                              const short* __restrict__ Zxbf,
                                              const float* __restrict__ zlab,
                                              short* __restrict__ Gacc,
                                              float* __restrict__ gcolacc) {
  __shared__ float zl[256];
  const int x = blockIdx.x, tid = threadIdx.x;
  if (x >= 512) {
    const int idx = x - 512, b = idx & 7, seg = idx >> 3;
    zl[tid] = zlab[b * NTOK + seg * 256 + tid];
    __syncthreads();
    const short* base = Zxbf + ((size_t)b * NTOK + seg * 256) * DD + tid;
    float s = 0.f;
    #pragma unroll 8
    for (int m = 0; m < 256; ++m) s += b2f(base[(size_t)m * DD]) * zl[m];
    gcolacc[(seg * 8 + b) * 256 + tid] = s;
    return;
  }
  const int lane = tid & 63, wid = tid >> 6;
  const int b = x & 7, t = (x >> 3) & 3, seg = x >> 5;
  const int r0 = (t >> 1) * 128, c0 = (t & 1) * 128;
  const int ar = r0 + (wid >> 1) * 64, bc = c0 + (wid & 1) * 64;
  const short* A = Zxt + (size_t)b * DD * NTOK;
  f32x4 acc[4][4];
  #pragma unroll
  for (int f = 0; f < 4; ++f) for (int g = 0; g < 4; ++g) for (int i = 0; i < 4; ++i) acc[f][g][i] = 0.f;
  mm64(A, A, NTOK, NTOK, ar, bc, seg * 128, seg * 128 + 128, lane, acc);
  short* out = Gacc + (size_t)(seg * 8 + b) * 65536;
  #pragma unroll
  for (int f = 0; f < 4; ++f) {
    const int rb = ar + f * 16 + ((lane >> 4) << 2);
    #pragma unroll
    for (int g = 0; g < 4; ++g) {
      const int col = bc + g * 16 + (lane & 15);
      short4v p;
      #pragma unroll
      for (int i = 0; i < 4; ++i) p[i] = (short)f2b(acc[f][g][i]);
      *(short4v*)(out + (size_t)col * 256 + rb) = p;   // transposed, contiguous 8B
    }
  }
}

// ---- k_gred: grid 264. x<256: b=x&7, linear 16-seg bf16 reduce -> Gbf (16B ld/st).
//      x>=256: gcol 8-seg reduce.
__global__ __launch_bounds__(256) void k_gred(const short* __restrict__ Gacc,
                                              const float* __restrict__ gcolacc,
                                              short* __restrict__ Gbf, float* __restrict__ gcol) {
  const int x = blockIdx.x, tid = threadIdx.x;
  if (x >= 256) {
    const int b = x - 256;
    float s = 0.f;
    #pragma unroll
    for (int seg = 0; seg < 8; ++seg) s += gcolacc[(seg * 8 + b) * 256 + tid];
    gcol[b * 256 + tid] = s;
    return;
  }
  const int b = x & 7, chunk = x >> 3;
  const int i0 = chunk * 2048 + tid * 8;
  float s[8] = {};
  #pragma unroll
  for (int seg = 0; seg < 16; ++seg) {
    short8v v = *(const short8v*)(Gacc + (size_t)(seg * 8 + b) * 65536 + i0);
    #pragma unroll
    for (int q = 0; q < 8; ++q) s[q] += b2f(v[q]);
  }
  short8v o;
  #pragma unroll
  for (int q = 0; q < 8; ++q) o[q] = (short)f2b(s[q]);
  *(short8v*)(Gbf + (size_t)b * 65536 + i0) = o;
}

// ---- k_pv: grid 264. x<256: b=x&7, t=x>>3: 128t x 128jc tile of V = G Pcat^T;
//      write Vt3[b][c][j*256+t]. x>=256: mcol = invN * QsumT gcol (coalesced).
__global__ __launch_bounds__(256) void k_pv(const short* __restrict__ Gbf, const short* __restrict__ Pbf,
                                            const float* __restrict__ QsumT, const float* __restrict__ gcol,
                                            short* __restrict__ Vt3, float* __restrict__ mcol, int layer) {
  __shared__ float gs[256];
  const int x = blockIdx.x, tid = threadIdx.x;
  if (x >= 256) {
    const int b = x - 256;
    gs[tid] = gcol[b * 256 + tid];
    __syncthreads();
    float s = 0.f;
    for (int t = 0; t < 256; ++t) s += QsumT[(size_t)layer * 65536 + (size_t)t * 256 + tid] * gs[t];
    mcol[b * 256 + tid] = s * (1.0f / (float)NVAL);
    return;
  }
  const int lane = tid & 63, wid = tid >> 6;
  const int b = x & 7, t = x >> 3;
  const int r0 = (t & 1) * 128, c0 = (t >> 1) * 128;   // r0: t-dim, c0: jc-dim
  const int ar = r0 + (wid >> 1) * 64, bc = c0 + (wid & 1) * 64;
  const short* A = Gbf + (size_t)b * 65536;
  const short* B = Pbf + (size_t)layer * 8 * 65536;
  f32x4 acc[4][4];
  #pragma unroll
  for (int f = 0; f < 4; ++f) for (int g = 0; g < 4; ++g) for (int i = 0; i < 4; ++i) acc[f][g][i] = 0.f;
  mm64(A, B, 256, 256, ar, bc, 0, 256, lane, acc);
  short* out = Vt3 + (size_t)b * 524288;
  #pragma unroll
  for (int f = 0; f < 4; ++f) {
    const int tt0 = ar + f * 16 + ((lane >> 4) << 2);
    #pragma unroll
    for (int g = 0; g < 4; ++g) {
      const int jc = bc + g * 16 + (lane & 15);
      const int j = jc >> 8, c = jc & 255;
      short4v p;
      #pragma unroll
      for (int i = 0; i < 4; ++i) p[i] = (short)f2b(acc[f][g][i]);
      *(short4v*)(out + (size_t)c * 2048 + j * 256 + tt0) = p;
    }
  }
}

// ---- k_qm: grid 512. b=x&7, tile=(x>>3)&3 (128k x 128c of M), seg=x>>5 (K=128 of jt).
//      A'=Qcat2[l] rows k, B'=Vt3[b] rows c -> out[k][c]; bf16 partial stored
//      TRANSPOSED => Macc[seg][b][c*256+k] (contiguous short4, == Mt layout).
__global__ __launch_bounds__(256) void k_qm(const short* __restrict__ Vt3, const short* __restrict__ Qcat2,
                                            short* __restrict__ Macc, int layer) {
  const int x = blockIdx.x, tid = threadIdx.x;
  const int lane = tid & 63, wid = tid >> 6;
  const int b = x & 7, t = (x >> 3) & 3, seg = x >> 5;
  const int r0 = (t >> 1) * 128, c0 = (t & 1) * 128;   // r0: k-dim, c0: c-dim
  const int ar = r0 + (wid >> 1) * 64, bc = c0 + (wid & 1) * 64;
  const short* A = Qcat2 + (size_t)layer * 524288;
  const short* B = Vt3 + (size_t)b * 524288;
  f32x4 acc[4][4];
  #pragma unroll
  for (int f = 0; f < 4; ++f) for (int g = 0; g < 4; ++g) for (int i = 0; i < 4; ++i) acc[f][g][i] = 0.f;
  mm64(A, B, 2048, 2048, ar, bc, seg * 128, seg * 128 + 128, lane, acc);
  short* out = Macc + (size_t)(seg * 8 + b) * 65536;
  #pragma unroll
  for (int f = 0; f < 4; ++f) {
    const int kb = ar + f * 16 + ((lane >> 4) << 2);
    #pragma unroll
    for (int g = 0; g < 4; ++g) {
      const int c = bc + g * 16 + (lane & 15);
      short4v p;
      #pragma unroll
      for (int i = 0; i < 4; ++i) p[i] = (short)f2b(acc[f][g][i]);
      *(short4v*)(out + (size_t)c * 256 + kb) = p;     // [c][k] layout, contiguous 8B
    }
  }
}

// ---- k_mred: grid 256. b=x&7, linear 16-seg bf16 reduce, *invN -> Mt[b][c][k].
__global__ __launch_bounds__(256) void k_mred(const short* __restrict__ Macc, short* __restrict__ Mt) {
  const int x = blockIdx.x, tid = threadIdx.x;
  const int b = x & 7, chunk = x >> 3;
  const int i0 = chunk * 2048 + tid * 8;
  float s[8] = {};
  #pragma unroll
  for (int seg = 0; seg < 16; ++seg) {
    short8v v = *(const short8v*)(Macc + (size_t)(seg * 8 + b) * 65536 + i0);
    #pragma unroll
    for (int q = 0; q < 8; ++q) s[q] += b2f(v[q]);
  }
  const float invN = 1.0f / (float)NVAL;
  short8v o;
  #pragma unroll
  for (int q = 0; q < 8; ++q) o[q] = (short)f2b(s[q] * invN);
  *(short8v*)(Mt + (size_t)b * 65536 + i0) = o;
}

// ---- k_apply: grid 256. b=x&7, t=x>>3: 128n x 128c tile.
//      Residual carried in BF16: res = b2f(Zxin) + acc. Intermediate layers
//      write only bf16 staging (Zxout, Zxt, zlab/zlabtrue); final layer (wnext=0)
//      writes fp32 d_out for all 257 columns.
__global__ __launch_bounds__(256) void k_apply(const short* __restrict__ Zxin, const short* __restrict__ Mt,
                                               const float* __restrict__ mcol,
                                               short* __restrict__ Zxout, short* __restrict__ Zxt_out,
                                               float* __restrict__ zlab, float* __restrict__ zlabtrue,
                                               float* __restrict__ dout, int wnext) {
  __shared__ short ldsT[128][136];
  const int tid = threadIdx.x, lane = tid & 63, wid = tid >> 6;
  const int wr = wid >> 1, wc = wid & 1;
  const int x = blockIdx.x;
  const int b = x & 7, t = x >> 3;
  const int ar_wg = (t >> 1) * 128, bc_wg = (t & 1) * 128;
  const int ar = ar_wg + wr * 64, bc = bc_wg + wc * 64;
  const short* A = Zxin + (size_t)b * NTOK * DD;
  const short* B = Mt + (size_t)b * 65536;
  const bool gemv = ((t & 1) == 0 && wc == 0);
  f32x4 acc[4][4];
  #pragma unroll
  for (int f = 0; f < 4; ++f) for (int g = 0; g < 4; ++g) for (int i = 0; i < 4; ++i) acc[f][g][i] = 0.f;
  float s[4] = {0.f, 0.f, 0.f, 0.f};
  #pragma unroll 2
  for (int kk = 0; kk < 256; kk += 32) {
    const int kc = kk + ((lane >> 4) << 3);
    short8v av[4], bv[4];
    #pragma unroll
    for (int f = 0; f < 4; ++f)
      av[f] = *(const short8v*)(A + (size_t)(ar + f * 16 + (lane & 15)) * DD + kc);
    #pragma unroll
    for (int g = 0; g < 4; ++g)
      bv[g] = *(const short8v*)(B + (size_t)(bc + g * 16 + (lane & 15)) * 256 + kc);
    if (gemv) {
      const float* mp = mcol + b * 256 + kc;
      f32x4 m0 = *(const f32x4*)mp, m1 = *(const f32x4*)(mp + 4);
      #pragma unroll
      for (int f = 0; f < 4; ++f) {
        #pragma unroll
        for (int q = 0; q < 4; ++q) {
          s[f] += b2f(av[f][q]) * m0[q];
          s[f] += b2f(av[f][4 + q]) * m1[q];
        }
      }
    }
    #pragma unroll
    for (int f = 0; f < 4; ++f)
      #pragma unroll
      for (int g = 0; g < 4; ++g)
        acc[f][g] = __builtin_amdgcn_mfma_f32_16x16x32_bf16(av[f], bv[g], acc[f][g], 0, 0, 0);
  }
  #pragma unroll
  for (int f = 0; f < 4; ++f) {
    const int nb = ar + f * 16 + ((lane >> 4) << 2);
    #pragma unroll
    for (int g = 0; g < 4; ++g) {
      const int c = bc + g * 16 + (lane & 15);
      #pragma unroll
      for (int i = 0; i < 4; ++i) {
        const size_t ridx = ((size_t)b * NTOK + nb + i) * DD + c;
        float nv = b2f(Zxin[ridx]) + acc[f][g][i];
        if (wnext) {
          unsigned short bvv = f2b(nv);
          Zxout[ridx] = (short)bvv;
          ldsT[c - bc_wg][nb - ar_wg + i] = (nb + i == NVAL) ? (short)0 : (short)bvv;
        } else {
          dout[((size_t)b * NTOK + nb + i) * NCH + c] = nv;
        }
      }
    }
  }
  if (gemv) {
    #pragma unroll
    for (int f = 0; f < 4; ++f) {
      float tt = s[f];
      tt += __shfl_xor(tt, 16);
      tt += __shfl_xor(tt, 32);
      if ((lane >> 4) == 0) {
        int n = ar + f * 16 + (lane & 15);
        float nv = zlabtrue[b * NTOK + n] + tt;
        if (wnext) {
          zlabtrue[b * NTOK + n] = nv;
          zlab[b * NTOK + n] = (n == NVAL) ? 0.f : nv;
        } else {
          dout[((size_t)b * NTOK + n) * NCH + DD] = nv;
        }
      }
    }
  }
  if (wnext) {
    __syncthreads();
    const int n0 = (tid & 15) * 8, cr0 = (tid >> 4) * 8;
    #pragma unroll
    for (int r = 0; r < 8; ++r) {
      short8v v = *(const short8v*)&ldsT[cr0 + r][n0];
      *(short8v*)(Zxt_out + ((size_t)b * DD + bc_wg + cr0 + r) * NTOK + ar_wg + n0) = v;
    }
  }
}

// =====================================================================================
extern "C" void kernel_launch(void* const* d_in, const int* in_sizes, int n_in,
                              void* d_out, int out_size, void* d_ws, size_t ws_size,
                              hipStream_t stream) {
  const float* Zin      = (const float*)d_in[0];
  const float* allparam = (const float*)d_in[1];
  float* Z = (float*)d_out;

  // ws layout (bytes)
  const size_t o_zx0  = 0;                         // bf16 [8][2048][256]    8,388,608 (ping)
  const size_t o_zx1  = o_zx0  + 8388608;          // bf16                   8,388,608 (pong)
  const size_t o_zxt  = o_zx1  + 8388608;          // bf16 [8][256][2048]    8,388,608
  const size_t o_acc  = o_zxt  + 8388608;          // bf16 [16][8][256][256] 16,777,216 (Gacc/Macc alias)
  const size_t o_gbf  = o_acc  + 16777216;         // bf16 [8][256][256]     1,048,576
  const size_t o_vt   = o_gbf  + 1048576;          // bf16 [8][256][2048]    8,388,608 (Vt3)
  const size_t o_mt   = o_vt   + 8388608;          // bf16 [8][256][256]     1,048,576
  const size_t o_pbf  = o_mt   + 1048576;          // bf16 [4][8][256][256]  4,194,304
  const size_t o_qc2  = o_pbf  + 4194304;          // bf16 [4][256][2048]    4,194,304 (Qcat2)
  const size_t o_qsum = o_qc2  + 4194304;          // f32  [4][256][256]     1,048,576
  const size_t o_gca  = o_qsum + 1048576;          // f32  [8][8][256]       65,536 (gcolacc)
  const size_t o_gcol = o_gca  + 65536;            // f32  [8][256]          8,192
  const size_t o_mcol = o_gcol + 8192;             // f32  [8][256]          8,192
  const size_t o_zlab = o_mcol + 8192;             // f32  [8][2048]         65,536
  const size_t o_zlt  = o_zlab + 65536;            // f32  [8][2048]         65,536 (zlabtrue)
  const size_t NEED   = o_zlt  + 65536;
  if (ws_size < NEED) return;                      // harness ws is larger; never hit

  char* wsb = (char*)d_ws;
  short* Zx[2]   = { (short*)(wsb + o_zx0), (short*)(wsb + o_zx1) };
  short* Zxt     = (short*)(wsb + o_zxt);
  short* Acc     = (short*)(wsb + o_acc);
  short* Gbf     = (short*)(wsb + o_gbf);
  short* Vt3     = (short*)(wsb + o_vt);
  short* Mt      = (short*)(wsb + o_mt);
  short* Pbf     = (short*)(wsb + o_pbf);
  short* Qcat2   = (short*)(wsb + o_qc2);
  float* QsumT   = (float*)(wsb + o_qsum);
  float* gcolacc = (float*)(wsb + o_gca);
  float* gcol    = (float*)(wsb + o_gcol);
  float* mcol    = (float*)(wsb + o_mcol);
  float* zlab    = (float*)(wsb + o_zlab);
  float* zlabtrue= (float*)(wsb + o_zlt);

  k_init<<<dim3(3136), dim3(256), 0, stream>>>(Zin, allparam, Pbf, Qcat2, QsumT,
                                               Zx[0], Zxt, zlab, zlabtrue);

  for (int layer = 0; layer < NL; ++layer) {
    const int cur = layer & 1;
    const int wnext = (layer < NL - 1) ? 1 : 0;
    k_gram<<<dim3(576), dim3(256), 0, stream>>>(Zxt, Zx[cur], zlab, Acc, gcolacc);
    k_gred<<<dim3(264), dim3(256), 0, stream>>>(Acc, gcolacc, Gbf, gcol);
    k_pv<<<dim3(264), dim3(256), 0, stream>>>(Gbf, Pbf, QsumT, gcol, Vt3, mcol, layer);
    k_qm<<<dim3(512), dim3(256), 0, stream>>>(Vt3, Qcat2, Acc, layer);
    k_mred<<<dim3(256), dim3(256), 0, stream>>>(Acc, Mt);
    k_apply<<<dim3(256), dim3(256), 0, stream>>>(Zx[cur], Mt, mcol,
                                                 Zx[cur ^ 1], Zxt, zlab, zlabtrue,
                                                 Z, wnext);
  }
}

// Round 12
// 354.284 us; speedup vs baseline: 1.3138x; 1.0118x over previous
//
#include <hip/hip_runtime.h>

// MetaTransformer collapse: per layer,
//   G[b]  = Zx[b,:2047]^T Zx[b,:2047]   (256x256, symmetric)   gcol = Zx^T zlab
//   V     = G Pcat^T  (256 x 2048 stacked heads);  M = Qcat2 (Vt3)^T  (K=2048)
//   mcol  = (1/N) QsumT^T gcol
//   Z[b] += Zx[b] M[b]  (+ label-col GEMV with mcol)
// Residual carried in BF16 (Zx ping-pong) + fp32 zlabtrue; fp32 d_out written
// only in the final layer. Split-K-16 bf16 transposed partials; gram computes
// 3 quadrants (symmetry mirror). pv/apply use 64x128 wg tiles (512 wgs, 2
// waves/SIMD). XCD-aligned b = x&7 everywhere. 25 dispatches.

#define NL   4
#define NH   8
#define DD   256
#define NCH  257
#define NTOK 2048
#define NVAL 2047
#define NB   8

typedef short  short8v __attribute__((ext_vector_type(8)));
typedef short  short4v __attribute__((ext_vector_type(4)));
typedef float  f32x4   __attribute__((ext_vector_type(4)));

__device__ __forceinline__ unsigned short f2b(float x) {
  union { float f; unsigned u; } v; v.f = x;
  unsigned u = v.u + 0x7fffu + ((v.u >> 16) & 1u);
  return (unsigned short)(u >> 16);
}
__device__ __forceinline__ float b2f(short s) {
  union { unsigned u; float f; } v; v.u = ((unsigned)(unsigned short)s) << 16;
  return v.f;
}

// ---- MFMA tile: one wave computes (NF*16) x (NG*16), K in [k0,k1).
template <int NF, int NG>
__device__ __forceinline__ void mm_t(const short* A, const short* B, int lda, int ldb,
                                     int ar, int bc, int k0, int k1, int lane,
                                     f32x4 (&acc)[NF][NG]) {
  #pragma unroll 2
  for (int kk = k0; kk < k1; kk += 32) {
    const int kc = kk + ((lane >> 4) << 3);
    short8v av[NF], bv[NG];
    #pragma unroll
    for (int f = 0; f < NF; ++f)
      av[f] = *(const short8v*)(A + (size_t)(ar + f * 16 + (lane & 15)) * lda + kc);
    #pragma unroll
    for (int g = 0; g < NG; ++g)
      bv[g] = *(const short8v*)(B + (size_t)(bc + g * 16 + (lane & 15)) * ldb + kc);
    #pragma unroll
    for (int f = 0; f < NF; ++f)
      #pragma unroll
      for (int g = 0; g < NG; ++g)
        acc[f][g] = __builtin_amdgcn_mfma_f32_16x16x32_bf16(av[f], bv[g], acc[f][g], 0, 0, 0);
  }
}

// ---- k_init: flat grid 3136.
//   [0,1024)     P cast -> Pbf
//   [1024,2048)  Q permute-cast -> Qcat2[l][k][j*256+t]
//   [2048,2112)  QsumT[l][t][k] = sum_j Q_j[k][t]  (fp32)
//   [2112,3136)  Zin -> Zxbf (natural bf16), Zxt (transposed, m=2047 zeroed),
//                zlab (zeroed @ NVAL) + zlabtrue (exact)
__global__ __launch_bounds__(256) void k_init(const float* __restrict__ Zin,
                                              const float* __restrict__ ap,
                                              short* __restrict__ Pbf, short* __restrict__ Qcat2,
                                              float* __restrict__ QsumT,
                                              short* __restrict__ Zxbf, short* __restrict__ Zxt,
                                              float* __restrict__ zlab, float* __restrict__ zlabtrue) {
  __shared__ float lds[64][65];
  const int bx = blockIdx.x, tid = threadIdx.x;
  if (bx < 1024) {
    const f32x4* src = (const f32x4*)ap;
    int q0 = (bx * 256 + tid) * 2;
    #pragma unroll
    for (int u = 0; u < 2; ++u) {
      int q = q0 + u, lj = q >> 14, rc4 = q & 16383;
      f32x4 v = src[(size_t)(lj * 2) * 16384 + rc4];
      short4v o;
      #pragma unroll
      for (int i = 0; i < 4; ++i) o[i] = (short)f2b(v[i]);
      ((short4v*)Pbf)[(size_t)lj * 16384 + rc4] = o;
    }
    return;
  }
  if (bx < 2048) {
    int idx = bx - 1024;
    int l = idx >> 8, k = idx & 255;
    int j = tid >> 5, t0 = (tid & 31) * 8;
    const float* s = ap + (size_t)((l * 8 + j) * 2 + 1) * 65536 + (size_t)k * 256 + t0;
    f32x4 a = *(const f32x4*)s, bq = *(const f32x4*)(s + 4);
    short8v o;
    #pragma unroll
    for (int i = 0; i < 4; ++i) { o[i] = (short)f2b(a[i]); o[4 + i] = (short)f2b(bq[i]); }
    *(short8v*)(Qcat2 + (size_t)(l * 256 + k) * 2048 + j * 256 + t0) = o;
    return;
  }
  if (bx < 2112) {
    int qb = bx - 2048;
    int l = qb >> 4, xx = qb & 15;
    int k0 = (xx >> 2) * 64, t0 = (xx & 3) * 64;
    int c = tid & 63, r = tid >> 6;
    #pragma unroll
    for (int i = 0; i < 16; ++i) {
      int k = r + i * 4;
      float s = 0.f;
      #pragma unroll
      for (int j = 0; j < 8; ++j)
        s += ap[(size_t)((l * 8 + j) * 2 + 1) * 65536 + (size_t)(k0 + k) * 256 + (t0 + c)];
      lds[k][c] = s;
    }
    __syncthreads();
    #pragma unroll
    for (int i = 0; i < 16; ++i) {
      int tl = r + i * 4;
      QsumT[(size_t)l * 65536 + (size_t)(t0 + tl) * 256 + (k0 + c)] = lds[c][tl];
    }
    return;
  }
  int tb = bx - 2112;
  int x = tb & 3, y = (tb >> 2) & 31, b = tb >> 7;
  int k0 = x * 64, m0 = y * 64;
  int c = tid & 63, r = tid >> 6;
  #pragma unroll
  for (int i = 0; i < 16; ++i) {
    int mrow = r + i * 4, m = m0 + mrow;
    float v = Zin[((size_t)b * NTOK + m) * NCH + k0 + c];
    lds[mrow][c] = v;
    Zxbf[((size_t)b * NTOK + m) * DD + k0 + c] = (short)f2b(v);
  }
  if (x == 0 && tid < 64) {
    int m = m0 + tid;
    float lv = Zin[((size_t)b * NTOK + m) * NCH + DD];
    zlabtrue[b * NTOK + m] = lv;
    zlab[b * NTOK + m] = (m == NVAL) ? 0.f : lv;
  }
  __syncthreads();
  const int mt = tid & 15, kg = tid >> 4;
  #pragma unroll
  for (int i = 0; i < 4; ++i) {
    int krow = kg * 4 + i;
    int m4 = mt * 4;
    short4v o;
    #pragma unroll
    for (int q = 0; q < 4; ++q) {
      float v = lds[m4 + q][krow];
      o[q] = (m0 + m4 + q == NVAL) ? (short)0 : (short)f2b(v);
    }
    *(short4v*)(Zxt + ((size_t)b * DD + k0 + krow) * NTOK + m0 + m4) = o;
  }
}

// ---- k_gram: grid 448. x<384: b=x&7, r=x>>3 (0..47): q=r%3 quadrant, seg=r/3
//      (K=128 window). q=0: (0,0); q=1: (1,1); q=2: (0,1) + mirror into (1,0).
//      bf16 partials stored TRANSPOSED (col-major; G symmetric).
//      x>=384: gcol partials over 256-m segment via Zxbf.
__global__ __launch_bounds__(256) void k_gram(const short* __restrict__ Zxt,
                                              const short* __restrict__ Zxbf,
                                              const float* __restrict__ zlab,
                                              short* __restrict__ Gacc,
                                              float* __restrict__ gcolacc) {
  __shared__ float zl[256];
  const int x = blockIdx.x, tid = threadIdx.x;
  if (x >= 384) {
    const int idx = x - 384, b = idx & 7, seg = idx >> 3;
    zl[tid] = zlab[b * NTOK + seg * 256 + tid];
    __syncthreads();
    const short* base = Zxbf + ((size_t)b * NTOK + seg * 256) * DD + tid;
    float s = 0.f;
    #pragma unroll 8
    for (int m = 0; m < 256; ++m) s += b2f(base[(size_t)m * DD]) * zl[m];
    gcolacc[(seg * 8 + b) * 256 + tid] = s;
    return;
  }
  const int lane = tid & 63, wid = tid >> 6;
  const int b = x & 7, r = x >> 3;
  const int q = r % 3, seg = r / 3;
  const int r0 = (q == 1) ? 128 : 0;
  const int c0 = (q == 0) ? 0 : 128;
  const int ar = r0 + (wid >> 1) * 64, bc = c0 + (wid & 1) * 64;
  const short* A = Zxt + (size_t)b * DD * NTOK;
  f32x4 acc[4][4];
  #pragma unroll
  for (int f = 0; f < 4; ++f) for (int g = 0; g < 4; ++g) for (int i = 0; i < 4; ++i) acc[f][g][i] = 0.f;
  mm_t<4, 4>(A, A, NTOK, NTOK, ar, bc, seg * 128, seg * 128 + 128, lane, acc);
  short* out = Gacc + (size_t)(seg * 8 + b) * 65536;
  #pragma unroll
  for (int f = 0; f < 4; ++f) {
    const int rb = ar + f * 16 + ((lane >> 4) << 2);
    #pragma unroll
    for (int g = 0; g < 4; ++g) {
      const int col = bc + g * 16 + (lane & 15);
      short4v p;
      #pragma unroll
      for (int i = 0; i < 4; ++i) p[i] = (short)f2b(acc[f][g][i]);
      *(short4v*)(out + (size_t)col * 256 + rb) = p;     // transposed, contiguous 8B
      if (q == 2) {
        #pragma unroll
        for (int i = 0; i < 4; ++i)
          out[(size_t)(rb + i) * 256 + col] = p[i];      // mirror into (1,0)
      }
    }
  }
}

// ---- k_gred: grid 264. x<256: b=x&7, linear 16-seg bf16 reduce -> Gbf (16B ld/st).
//      x>=256: gcol 8-seg reduce.
__global__ __launch_bounds__(256) void k_gred(const short* __restrict__ Gacc,
                                              const float* __restrict__ gcolacc,
                                              short* __restrict__ Gbf, float* __restrict__ gcol) {
  const int x = blockIdx.x, tid = threadIdx.x;
  if (x >= 256) {
    const int b = x - 256;
    float s = 0.f;
    #pragma unroll
    for (int seg = 0; seg < 8; ++seg) s += gcolacc[(seg * 8 + b) * 256 + tid];
    gcol[b * 256 + tid] = s;
    return;
  }
  const int b = x & 7, chunk = x >> 3;
  const int i0 = chunk * 2048 + tid * 8;
  float s[8] = {};
  #pragma unroll
  for (int seg = 0; seg < 16; ++seg) {
    short8v v = *(const short8v*)(Gacc + (size_t)(seg * 8 + b) * 65536 + i0);
    #pragma unroll
    for (int q = 0; q < 8; ++q) s[q] += b2f(v[q]);
  }
  short8v o;
  #pragma unroll
  for (int q = 0; q < 8; ++q) o[q] = (short)f2b(s[q]);
  *(short8v*)(Gbf + (size_t)b * 65536 + i0) = o;
}

// ---- k_pv: grid 520. x<512: b=x&7, t=x>>3 (0..63): 64t x 128jc tile of
//      V = G Pcat^T (4 waves, each 64x32); write Vt3[b][c][j*256+t].
//      x>=512: mcol = invN * QsumT gcol (coalesced).
__global__ __launch_bounds__(256) void k_pv(const short* __restrict__ Gbf, const short* __restrict__ Pbf,
                                            const float* __restrict__ QsumT, const float* __restrict__ gcol,
                                            short* __restrict__ Vt3, float* __restrict__ mcol, int layer) {
  __shared__ float gs[256];
  const int x = blockIdx.x, tid = threadIdx.x;
  if (x >= 512) {
    const int b = x - 512;
    gs[tid] = gcol[b * 256 + tid];
    __syncthreads();
    float s = 0.f;
    for (int t = 0; t < 256; ++t) s += QsumT[(size_t)layer * 65536 + (size_t)t * 256 + tid] * gs[t];
    mcol[b * 256 + tid] = s * (1.0f / (float)NVAL);
    return;
  }
  const int lane = tid & 63, wid = tid >> 6;
  const int b = x & 7, t = x >> 3;
  const int r0 = (t & 3) * 64, jc0 = (t >> 2) * 128;
  const int bc = jc0 + wid * 32;
  const short* A = Gbf + (size_t)b * 65536;
  const short* B = Pbf + (size_t)layer * 8 * 65536;
  f32x4 acc[4][2];
  #pragma unroll
  for (int f = 0; f < 4; ++f) for (int g = 0; g < 2; ++g) for (int i = 0; i < 4; ++i) acc[f][g][i] = 0.f;
  mm_t<4, 2>(A, B, 256, 256, r0, bc, 0, 256, lane, acc);
  short* out = Vt3 + (size_t)b * 524288;
  #pragma unroll
  for (int f = 0; f < 4; ++f) {
    const int tt0 = r0 + f * 16 + ((lane >> 4) << 2);
    #pragma unroll
    for (int g = 0; g < 2; ++g) {
      const int jc = bc + g * 16 + (lane & 15);
      const int j = jc >> 8, c = jc & 255;
      short4v p;
      #pragma unroll
      for (int i = 0; i < 4; ++i) p[i] = (short)f2b(acc[f][g][i]);
      *(short4v*)(out + (size_t)c * 2048 + j * 256 + tt0) = p;
    }
  }
}

// ---- k_qm: grid 512. b=x&7, tile=(x>>3)&3 (128k x 128c of M), seg=x>>5 (K=128 of jt).
//      A'=Qcat2[l] rows k, B'=Vt3[b] rows c -> out[k][c]; bf16 partial stored
//      TRANSPOSED => Macc[seg][b][c*256+k] (contiguous short4, == Mt layout).
__global__ __launch_bounds__(256) void k_qm(const short* __restrict__ Vt3, const short* __restrict__ Qcat2,
                                            short* __restrict__ Macc, int layer) {
  const int x = blockIdx.x, tid = threadIdx.x;
  const int lane = tid & 63, wid = tid >> 6;
  const int b = x & 7, t = (x >> 3) & 3, seg = x >> 5;
  const int r0 = (t >> 1) * 128, c0 = (t & 1) * 128;   // r0: k-dim, c0: c-dim
  const int ar = r0 + (wid >> 1) * 64, bc = c0 + (wid & 1) * 64;
  const short* A = Qcat2 + (size_t)layer * 524288;
  const short* B = Vt3 + (size_t)b * 524288;
  f32x4 acc[4][4];
  #pragma unroll
  for (int f = 0; f < 4; ++f) for (int g = 0; g < 4; ++g) for (int i = 0; i < 4; ++i) acc[f][g][i] = 0.f;
  mm_t<4, 4>(A, B, 2048, 2048, ar, bc, seg * 128, seg * 128 + 128, lane, acc);
  short* out = Macc + (size_t)(seg * 8 + b) * 65536;
  #pragma unroll
  for (int f = 0; f < 4; ++f) {
    const int kb = ar + f * 16 + ((lane >> 4) << 2);
    #pragma unroll
    for (int g = 0; g < 4; ++g) {
      const int c = bc + g * 16 + (lane & 15);
      short4v p;
      #pragma unroll
      for (int i = 0; i < 4; ++i) p[i] = (short)f2b(acc[f][g][i]);
      *(short4v*)(out + (size_t)c * 256 + kb) = p;     // [c][k] layout, contiguous 8B
    }
  }
}

// ---- k_mred: grid 256. b=x&7, linear 16-seg bf16 reduce, *invN -> Mt[b][c][k].
__global__ __launch_bounds__(256) void k_mred(const short* __restrict__ Macc, short* __restrict__ Mt) {
  const int x = blockIdx.x, tid = threadIdx.x;
  const int b = x & 7, chunk = x >> 3;
  const int i0 = chunk * 2048 + tid * 8;
  float s[8] = {};
  #pragma unroll
  for (int seg = 0; seg < 16; ++seg) {
    short8v v = *(const short8v*)(Macc + (size_t)(seg * 8 + b) * 65536 + i0);
    #pragma unroll
    for (int q = 0; q < 8; ++q) s[q] += b2f(v[q]);
  }
  const float invN = 1.0f / (float)NVAL;
  short8v o;
  #pragma unroll
  for (int q = 0; q < 8; ++q) o[q] = (short)f2b(s[q] * invN);
  *(short8v*)(Mt + (size_t)b * 65536 + i0) = o;
}

// ---- k_apply: grid 512. b=x&7, t=x>>3 (0..63): 64n x 128c tile (4 waves, each
//      64x32). Residual in BF16: res = b2f(Zxin) + acc. Intermediate layers
//      write bf16 staging; final layer writes fp32 d_out.
__global__ __launch_bounds__(256) void k_apply(const short* __restrict__ Zxin, const short* __restrict__ Mt,
                                               const float* __restrict__ mcol,
                                               short* __restrict__ Zxout, short* __restrict__ Zxt_out,
                                               float* __restrict__ zlab, float* __restrict__ zlabtrue,
                                               float* __restrict__ dout, int wnext) {
  __shared__ short ldsT[128][72];
  const int tid = threadIdx.x, lane = tid & 63, wid = tid >> 6;
  const int x = blockIdx.x;
  const int b = x & 7, t = x >> 3;
  const int n0 = (t >> 1) * 64, c0 = (t & 1) * 128;
  const int bc = c0 + wid * 32;
  const short* A = Zxin + (size_t)b * NTOK * DD;
  const short* B = Mt + (size_t)b * 65536;
  const bool gemv = ((t & 1) == 0 && wid == 0);
  f32x4 acc[4][2];
  #pragma unroll
  for (int f = 0; f < 4; ++f) for (int g = 0; g < 2; ++g) for (int i = 0; i < 4; ++i) acc[f][g][i] = 0.f;
  float s[4] = {0.f, 0.f, 0.f, 0.f};
  #pragma unroll 2
  for (int kk = 0; kk < 256; kk += 32) {
    const int kc = kk + ((lane >> 4) << 3);
    short8v av[4], bv[2];
    #pragma unroll
    for (int f = 0; f < 4; ++f)
      av[f] = *(const short8v*)(A + (size_t)(n0 + f * 16 + (lane & 15)) * DD + kc);
    #pragma unroll
    for (int g = 0; g < 2; ++g)
      bv[g] = *(const short8v*)(B + (size_t)(bc + g * 16 + (lane & 15)) * 256 + kc);
    if (gemv) {
      const float* mp = mcol + b * 256 + kc;
      f32x4 m0 = *(const f32x4*)mp, m1 = *(const f32x4*)(mp + 4);
      #pragma unroll
      for (int f = 0; f < 4; ++f) {
        #pragma unroll
        for (int q = 0; q < 4; ++q) {
          s[f] += b2f(av[f][q]) * m0[q];
          s[f] += b2f(av[f][4 + q]) * m1[q];
        }
      }
    }
    #pragma unroll
    for (int f = 0; f < 4; ++f)
      #pragma unroll
      for (int g = 0; g < 2; ++g)
        acc[f][g] = __builtin_amdgcn_mfma_f32_16x16x32_bf16(av[f], bv[g], acc[f][g], 0, 0, 0);
  }
  #pragma unroll
  for (int f = 0; f < 4; ++f) {
    const int nb = n0 + f * 16 + ((lane >> 4) << 2);
    #pragma unroll
    for (int g = 0; g < 2; ++g) {
      const int c = bc + g * 16 + (lane & 15);
      #pragma unroll
      for (int i = 0; i < 4; ++i) {
        const size_t ridx = ((size_t)b * NTOK + nb + i) * DD + c;
        float nv = b2f(Zxin[ridx]) + acc[f][g][i];
        if (wnext) {
          unsigned short bvv = f2b(nv);
          Zxout[ridx] = (short)bvv;
          ldsT[c - c0][nb - n0 + i] = (nb + i == NVAL) ? (short)0 : (short)bvv;
        } else {
          dout[((size_t)b * NTOK + nb + i) * NCH + c] = nv;
        }
      }
    }
  }
  if (gemv) {
    #pragma unroll
    for (int f = 0; f < 4; ++f) {
      float tt = s[f];
      tt += __shfl_xor(tt, 16);
      tt += __shfl_xor(tt, 32);
      if ((lane >> 4) == 0) {
        int n = n0 + f * 16 + (lane & 15);
        float nv = zlabtrue[b * NTOK + n] + tt;
        if (wnext) {
          zlabtrue[b * NTOK + n] = nv;
          zlab[b * NTOK + n] = (n == NVAL) ? 0.f : nv;
        } else {
          dout[((size_t)b * NTOK + n) * NCH + DD] = nv;
        }
      }
    }
  }
  if (wnext) {
    __syncthreads();
    #pragma unroll
    for (int u = 0; u < 4; ++u) {
      const int e = tid + u * 256;
      const int cr = e >> 3, ch = e & 7;
      short8v v = *(const short8v*)&ldsT[cr][ch * 8];
      *(short8v*)(Zxt_out + ((size_t)b * DD + c0 + cr) * NTOK + n0 + ch * 8) = v;
    }
  }
}

// =====================================================================================
extern "C" void kernel_launch(void* const* d_in, const int* in_sizes, int n_in,
                              void* d_out, int out_size, void* d_ws, size_t ws_size,
                              hipStream_t stream) {
  const float* Zin      = (const float*)d_in[0];
  const float* allparam = (const float*)d_in[1];
  float* Z = (float*)d_out;

  // ws layout (bytes)
  const size_t o_zx0  = 0;                         // bf16 [8][2048][256]    8,388,608 (ping)
  const size_t o_zx1  = o_zx0  + 8388608;          // bf16                   8,388,608 (pong)
  const size_t o_zxt  = o_zx1  + 8388608;          // bf16 [8][256][2048]    8,388,608
  const size_t o_acc  = o_zxt  + 8388608;          // bf16 [16][8][256][256] 16,777,216 (Gacc/Macc alias)
  const size_t o_gbf  = o_acc  + 16777216;         // bf16 [8][256][256]     1,048,576
  const size_t o_vt   = o_gbf  + 1048576;          // bf16 [8][256][2048]    8,388,608 (Vt3)
  const size_t o_mt   = o_vt   + 8388608;          // bf16 [8][256][256]     1,048,576
  const size_t o_pbf  = o_mt   + 1048576;          // bf16 [4][8][256][256]  4,194,304
  const size_t o_qc2  = o_pbf  + 4194304;          // bf16 [4][256][2048]    4,194,304 (Qcat2)
  const size_t o_qsum = o_qc2  + 4194304;          // f32  [4][256][256]     1,048,576
  const size_t o_gca  = o_qsum + 1048576;          // f32  [8][8][256]       65,536 (gcolacc)
  const size_t o_gcol = o_gca  + 65536;            // f32  [8][256]          8,192
  const size_t o_mcol = o_gcol + 8192;             // f32  [8][256]          8,192
  const size_t o_zlab = o_mcol + 8192;             // f32  [8][2048]         65,536
  const size_t o_zlt  = o_zlab + 65536;            // f32  [8][2048]         65,536 (zlabtrue)
  const size_t NEED   = o_zlt  + 65536;
  if (ws_size < NEED) return;                      // harness ws is larger; never hit

  char* wsb = (char*)d_ws;
  short* Zx[2]   = { (short*)(wsb + o_zx0), (short*)(wsb + o_zx1) };
  short* Zxt     = (short*)(wsb + o_zxt);
  short* Acc     = (short*)(wsb + o_acc);
  short* Gbf     = (short*)(wsb + o_gbf);
  short* Vt3     = (short*)(wsb + o_vt);
  short* Mt      = (short*)(wsb + o_mt);
  short* Pbf     = (short*)(wsb + o_pbf);
  short* Qcat2   = (short*)(wsb + o_qc2);
  float* QsumT   = (float*)(wsb + o_qsum);
  float* gcolacc = (float*)(wsb + o_gca);
  float* gcol    = (float*)(wsb + o_gcol);
  float* mcol    = (float*)(wsb + o_mcol);
  float* zlab    = (float*)(wsb + o_zlab);
  float* zlabtrue= (float*)(wsb + o_zlt);

  k_init<<<dim3(3136), dim3(256), 0, stream>>>(Zin, allparam, Pbf, Qcat2, QsumT,
                                               Zx[0], Zxt, zlab, zlabtrue);

  for (int layer = 0; layer < NL; ++layer) {
    const int cur = layer & 1;
    const int wnext = (layer < NL - 1) ? 1 : 0;
    k_gram<<<dim3(448), dim3(256), 0, stream>>>(Zxt, Zx[cur], zlab, Acc, gcolacc);
    k_gred<<<dim3(264), dim3(256), 0, stream>>>(Acc, gcolacc, Gbf, gcol);
    k_pv<<<dim3(520), dim3(256), 0, stream>>>(Gbf, Pbf, QsumT, gcol, Vt3, mcol, layer);
    k_qm<<<dim3(512), dim3(256), 0, stream>>>(Vt3, Qcat2, Acc, layer);
    k_mred<<<dim3(256), dim3(256), 0, stream>>>(Acc, Mt);
    k_apply<<<dim3(512), dim3(256), 0, stream>>>(Zx[cur], Mt, mcol,
                                                 Zx[cur ^ 1], Zxt, zlab, zlabtrue,
                                                 Z, wnext);
  }
}

// Round 13
// 345.946 us; speedup vs baseline: 1.3455x; 1.0241x over previous
//
#include <hip/hip_runtime.h>

// MetaTransformer collapse: per layer,
//   G[b]  = Zx[b,:2047]^T Zx[b,:2047]   (256x256, symmetric)   gcol = Zx^T zlab
//   V     = G Pcat^T  (256 x 2048 stacked heads);  M = Qcat2 (Vt3)^T  (K=2048)
//   mcol  = (1/N) QsumT^T gcol
//   Z[b] += Zx[b] M[b]  (+ label-col GEMV with mcol)
// Residual carried in BF16 (Zx ping-pong) + fp32 zlabtrue; fp32 d_out written
// only in the final layer. Split-K-16 bf16 transposed partials; gram computes
// 3 quadrants (symmetry mirror). mm_t uses a manual double-buffered K-loop
// (next step's loads issued before current step's MFMAs -> counted-vmcnt
// pipelining). XCD-aligned b = x&7 everywhere. 25 dispatches.

#define NL   4
#define NH   8
#define DD   256
#define NCH  257
#define NTOK 2048
#define NVAL 2047
#define NB   8

typedef short  short8v __attribute__((ext_vector_type(8)));
typedef short  short4v __attribute__((ext_vector_type(4)));
typedef float  f32x4   __attribute__((ext_vector_type(4)));

__device__ __forceinline__ unsigned short f2b(float x) {
  union { float f; unsigned u; } v; v.f = x;
  unsigned u = v.u + 0x7fffu + ((v.u >> 16) & 1u);
  return (unsigned short)(u >> 16);
}
__device__ __forceinline__ float b2f(short s) {
  union { unsigned u; float f; } v; v.u = ((unsigned)(unsigned short)s) << 16;
  return v.f;
}

// ---- MFMA tile, double-buffered K-loop: one wave computes (NF*16)x(NG*16).
// K range [k0,k1) must be a multiple of 64 (all call sites are).
template <int NF, int NG>
__device__ __forceinline__ void mm_t(const short* A, const short* B, int lda, int ldb,
                                     int ar, int bc, int k0, int k1, int lane,
                                     f32x4 (&acc)[NF][NG]) {
  const int kc = (lane >> 4) << 3;
  const int al = lane & 15;
  short8v a0[NF], b0[NG], a1[NF], b1[NG];
  #pragma unroll
  for (int f = 0; f < NF; ++f) a0[f] = *(const short8v*)(A + (size_t)(ar + f * 16 + al) * lda + k0 + kc);
  #pragma unroll
  for (int g = 0; g < NG; ++g) b0[g] = *(const short8v*)(B + (size_t)(bc + g * 16 + al) * ldb + k0 + kc);
  for (int kk = k0 + 32; kk < k1; kk += 64) {
    // issue loads for step kk while MFMAs consume step kk-32
    #pragma unroll
    for (int f = 0; f < NF; ++f) a1[f] = *(const short8v*)(A + (size_t)(ar + f * 16 + al) * lda + kk + kc);
    #pragma unroll
    for (int g = 0; g < NG; ++g) b1[g] = *(const short8v*)(B + (size_t)(bc + g * 16 + al) * ldb + kk + kc);
    #pragma unroll
    for (int f = 0; f < NF; ++f)
      #pragma unroll
      for (int g = 0; g < NG; ++g)
        acc[f][g] = __builtin_amdgcn_mfma_f32_16x16x32_bf16(a0[f], b0[g], acc[f][g], 0, 0, 0);
    if (kk + 32 < k1) {
      #pragma unroll
      for (int f = 0; f < NF; ++f) a0[f] = *(const short8v*)(A + (size_t)(ar + f * 16 + al) * lda + kk + 32 + kc);
      #pragma unroll
      for (int g = 0; g < NG; ++g) b0[g] = *(const short8v*)(B + (size_t)(bc + g * 16 + al) * ldb + kk + 32 + kc);
    }
    #pragma unroll
    for (int f = 0; f < NF; ++f)
      #pragma unroll
      for (int g = 0; g < NG; ++g)
        acc[f][g] = __builtin_amdgcn_mfma_f32_16x16x32_bf16(a1[f], b1[g], acc[f][g], 0, 0, 0);
  }
}

// ---- k_init: flat grid 3136.
//   [0,1024)     P cast -> Pbf
//   [1024,2048)  Q permute-cast -> Qcat2[l][k][j*256+t]
//   [2048,2112)  QsumT[l][t][k] = sum_j Q_j[k][t]  (fp32)
//   [2112,3136)  Zin -> Zxbf (natural bf16), Zxt (transposed, m=2047 zeroed),
//                zlab (zeroed @ NVAL) + zlabtrue (exact). float4 Zin loads.
__global__ __launch_bounds__(256) void k_init(const float* __restrict__ Zin,
                                              const float* __restrict__ ap,
                                              short* __restrict__ Pbf, short* __restrict__ Qcat2,
                                              float* __restrict__ QsumT,
                                              short* __restrict__ Zxbf, short* __restrict__ Zxt,
                                              float* __restrict__ zlab, float* __restrict__ zlabtrue) {
  __shared__ float lds[64][65];
  const int bx = blockIdx.x, tid = threadIdx.x;
  if (bx < 1024) {
    const f32x4* src = (const f32x4*)ap;
    int q0 = (bx * 256 + tid) * 2;
    #pragma unroll
    for (int u = 0; u < 2; ++u) {
      int q = q0 + u, lj = q >> 14, rc4 = q & 16383;
      f32x4 v = src[(size_t)(lj * 2) * 16384 + rc4];
      short4v o;
      #pragma unroll
      for (int i = 0; i < 4; ++i) o[i] = (short)f2b(v[i]);
      ((short4v*)Pbf)[(size_t)lj * 16384 + rc4] = o;
    }
    return;
  }
  if (bx < 2048) {
    int idx = bx - 1024;
    int l = idx >> 8, k = idx & 255;
    int j = tid >> 5, t0 = (tid & 31) * 8;
    const float* s = ap + (size_t)((l * 8 + j) * 2 + 1) * 65536 + (size_t)k * 256 + t0;
    f32x4 a = *(const f32x4*)s, bq = *(const f32x4*)(s + 4);
    short8v o;
    #pragma unroll
    for (int i = 0; i < 4; ++i) { o[i] = (short)f2b(a[i]); o[4 + i] = (short)f2b(bq[i]); }
    *(short8v*)(Qcat2 + (size_t)(l * 256 + k) * 2048 + j * 256 + t0) = o;
    return;
  }
  if (bx < 2112) {
    int qb = bx - 2048;
    int l = qb >> 4, xx = qb & 15;
    int k0 = (xx >> 2) * 64, t0 = (xx & 3) * 64;
    int c = tid & 63, r = tid >> 6;
    #pragma unroll
    for (int i = 0; i < 16; ++i) {
      int k = r + i * 4;
      float s = 0.f;
      #pragma unroll
      for (int j = 0; j < 8; ++j)
        s += ap[(size_t)((l * 8 + j) * 2 + 1) * 65536 + (size_t)(k0 + k) * 256 + (t0 + c)];
      lds[k][c] = s;
    }
    __syncthreads();
    #pragma unroll
    for (int i = 0; i < 16; ++i) {
      int tl = r + i * 4;
      QsumT[(size_t)l * 65536 + (size_t)(t0 + tl) * 256 + (k0 + c)] = lds[c][tl];
    }
    return;
  }
  int tb = bx - 2112;
  int x = tb & 3, y = (tb >> 2) & 31, b = tb >> 7;
  int k0 = x * 64, m0 = y * 64;
  const int c4 = (tid & 15) * 4, rr = tid >> 4;   // 16 rows per pass, 4 passes
  #pragma unroll
  for (int i = 0; i < 4; ++i) {
    int mrow = rr + i * 16, m = m0 + mrow;
    f32x4 v = *(const f32x4*)(Zin + ((size_t)b * NTOK + m) * NCH + k0 + c4);
    short4v o;
    #pragma unroll
    for (int q = 0; q < 4; ++q) { lds[mrow][c4 + q] = v[q]; o[q] = (short)f2b(v[q]); }
    *(short4v*)(Zxbf + ((size_t)b * NTOK + m) * DD + k0 + c4) = o;
  }
  if (x == 0 && tid < 64) {
    int m = m0 + tid;
    float lv = Zin[((size_t)b * NTOK + m) * NCH + DD];
    zlabtrue[b * NTOK + m] = lv;
    zlab[b * NTOK + m] = (m == NVAL) ? 0.f : lv;
  }
  __syncthreads();
  const int mt = tid & 15, kg = tid >> 4;
  #pragma unroll
  for (int i = 0; i < 4; ++i) {
    int krow = kg * 4 + i;
    int m4 = mt * 4;
    short4v o;
    #pragma unroll
    for (int q = 0; q < 4; ++q) {
      float v = lds[m4 + q][krow];
      o[q] = (m0 + m4 + q == NVAL) ? (short)0 : (short)f2b(v);
    }
    *(short4v*)(Zxt + ((size_t)b * DD + k0 + krow) * NTOK + m0 + m4) = o;
  }
}

// ---- k_gram: grid 448. x<384: b=x&7, r=x>>3 (0..47): q=r%3 quadrant, seg=r/3
//      (K=128 window). q=0: (0,0); q=1: (1,1); q=2: (0,1) + mirror into (1,0).
//      bf16 partials stored TRANSPOSED (col-major; G symmetric).
//      x>=384: gcol partials over 256-m segment via Zxbf.
__global__ __launch_bounds__(256) void k_gram(const short* __restrict__ Zxt,
                                              const short* __restrict__ Zxbf,
                                              const float* __restrict__ zlab,
                                              short* __restrict__ Gacc,
                                              float* __restrict__ gcolacc) {
  __shared__ float zl[256];
  const int x = blockIdx.x, tid = threadIdx.x;
  if (x >= 384) {
    const int idx = x - 384, b = idx & 7, seg = idx >> 3;
    zl[tid] = zlab[b * NTOK + seg * 256 + tid];
    __syncthreads();
    const short* base = Zxbf + ((size_t)b * NTOK + seg * 256) * DD + tid;
    float s = 0.f;
    #pragma unroll 8
    for (int m = 0; m < 256; ++m) s += b2f(base[(size_t)m * DD]) * zl[m];
    gcolacc[(seg * 8 + b) * 256 + tid] = s;
    return;
  }
  const int lane = tid & 63, wid = tid >> 6;
  const int b = x & 7, r = x >> 3;
  const int q = r % 3, seg = r / 3;
  const int r0 = (q == 1) ? 128 : 0;
  const int c0 = (q == 0) ? 0 : 128;
  const int ar = r0 + (wid >> 1) * 64, bc = c0 + (wid & 1) * 64;
  const short* A = Zxt + (size_t)b * DD * NTOK;
  f32x4 acc[4][4];
  #pragma unroll
  for (int f = 0; f < 4; ++f) for (int g = 0; g < 4; ++g) for (int i = 0; i < 4; ++i) acc[f][g][i] = 0.f;
  mm_t<4, 4>(A, A, NTOK, NTOK, ar, bc, seg * 128, seg * 128 + 128, lane, acc);
  short* out = Gacc + (size_t)(seg * 8 + b) * 65536;
  #pragma unroll
  for (int f = 0; f < 4; ++f) {
    const int rb = ar + f * 16 + ((lane >> 4) << 2);
    #pragma unroll
    for (int g = 0; g < 4; ++g) {
      const int col = bc + g * 16 + (lane & 15);
      short4v p;
      #pragma unroll
      for (int i = 0; i < 4; ++i) p[i] = (short)f2b(acc[f][g][i]);
      *(short4v*)(out + (size_t)col * 256 + rb) = p;     // transposed, contiguous 8B
      if (q == 2) {
        #pragma unroll
        for (int i = 0; i < 4; ++i)
          out[(size_t)(rb + i) * 256 + col] = p[i];      // mirror into (1,0)
      }
    }
  }
}

// ---- k_gred: grid 264. x<256: b=x&7, linear 16-seg bf16 reduce -> Gbf (16B ld/st).
//      x>=256: gcol 8-seg reduce.
__global__ __launch_bounds__(256) void k_gred(const short* __restrict__ Gacc,
                                              const float* __restrict__ gcolacc,
                                              short* __restrict__ Gbf, float* __restrict__ gcol) {
  const int x = blockIdx.x, tid = threadIdx.x;
  if (x >= 256) {
    const int b = x - 256;
    float s = 0.f;
    #pragma unroll
    for (int seg = 0; seg < 8; ++seg) s += gcolacc[(seg * 8 + b) * 256 + tid];
    gcol[b * 256 + tid] = s;
    return;
  }
  const int b = x & 7, chunk = x >> 3;
  const int i0 = chunk * 2048 + tid * 8;
  float s[8] = {};
  #pragma unroll
  for (int seg = 0; seg < 16; ++seg) {
    short8v v = *(const short8v*)(Gacc + (size_t)(seg * 8 + b) * 65536 + i0);
    #pragma unroll
    for (int q = 0; q < 8; ++q) s[q] += b2f(v[q]);
  }
  short8v o;
  #pragma unroll
  for (int q = 0; q < 8; ++q) o[q] = (short)f2b(s[q]);
  *(short8v*)(Gbf + (size_t)b * 65536 + i0) = o;
}

// ---- k_pv: grid 520. x<512: b=x&7, t=x>>3 (0..63): 64t x 128jc tile of
//      V = G Pcat^T (4 waves, each 64x32); write Vt3[b][c][j*256+t].
//      x>=512: mcol = invN * QsumT gcol (coalesced).
__global__ __launch_bounds__(256) void k_pv(const short* __restrict__ Gbf, const short* __restrict__ Pbf,
                                            const float* __restrict__ QsumT, const float* __restrict__ gcol,
                                            short* __restrict__ Vt3, float* __restrict__ mcol, int layer) {
  __shared__ float gs[256];
  const int x = blockIdx.x, tid = threadIdx.x;
  if (x >= 512) {
    const int b = x - 512;
    gs[tid] = gcol[b * 256 + tid];
    __syncthreads();
    float s = 0.f;
    for (int t = 0; t < 256; ++t) s += QsumT[(size_t)layer * 65536 + (size_t)t * 256 + tid] * gs[t];
    mcol[b * 256 + tid] = s * (1.0f / (float)NVAL);
    return;
  }
  const int lane = tid & 63, wid = tid >> 6;
  const int b = x & 7, t = x >> 3;
  const int r0 = (t & 3) * 64, jc0 = (t >> 2) * 128;
  const int bc = jc0 + wid * 32;
  const short* A = Gbf + (size_t)b * 65536;
  const short* B = Pbf + (size_t)layer * 8 * 65536;
  f32x4 acc[4][2];
  #pragma unroll
  for (int f = 0; f < 4; ++f) for (int g = 0; g < 2; ++g) for (int i = 0; i < 4; ++i) acc[f][g][i] = 0.f;
  mm_t<4, 2>(A, B, 256, 256, r0, bc, 0, 256, lane, acc);
  short* out = Vt3 + (size_t)b * 524288;
  #pragma unroll
  for (int f = 0; f < 4; ++f) {
    const int tt0 = r0 + f * 16 + ((lane >> 4) << 2);
    #pragma unroll
    for (int g = 0; g < 2; ++g) {
      const int jc = bc + g * 16 + (lane & 15);
      const int j = jc >> 8, c = jc & 255;
      short4v p;
      #pragma unroll
      for (int i = 0; i < 4; ++i) p[i] = (short)f2b(acc[f][g][i]);
      *(short4v*)(out + (size_t)c * 2048 + j * 256 + tt0) = p;
    }
  }
}

// ---- k_qm: grid 512. b=x&7, tile=(x>>3)&3 (128k x 128c of M), seg=x>>5 (K=128 of jt).
//      A'=Qcat2[l] rows k, B'=Vt3[b] rows c -> out[k][c]; bf16 partial stored
//      TRANSPOSED => Macc[seg][b][c*256+k] (contiguous short4, == Mt layout).
__global__ __launch_bounds__(256) void k_qm(const short* __restrict__ Vt3, const short* __restrict__ Qcat2,
                                            short* __restrict__ Macc, int layer) {
  const int x = blockIdx.x, tid = threadIdx.x;
  const int lane = tid & 63, wid = tid >> 6;
  const int b = x & 7, t = (x >> 3) & 3, seg = x >> 5;
  const int r0 = (t >> 1) * 128, c0 = (t & 1) * 128;   // r0: k-dim, c0: c-dim
  const int ar = r0 + (wid >> 1) * 64, bc = c0 + (wid & 1) * 64;
  const short* A = Qcat2 + (size_t)layer * 524288;
  const short* B = Vt3 + (size_t)b * 524288;
  f32x4 acc[4][4];
  #pragma unroll
  for (int f = 0; f < 4; ++f) for (int g = 0; g < 4; ++g) for (int i = 0; i < 4; ++i) acc[f][g][i] = 0.f;
  mm_t<4, 4>(A, B, 2048, 2048, ar, bc, seg * 128, seg * 128 + 128, lane, acc);
  short* out = Macc + (size_t)(seg * 8 + b) * 65536;
  #pragma unroll
  for (int f = 0; f < 4; ++f) {
    const int kb = ar + f * 16 + ((lane >> 4) << 2);
    #pragma unroll
    for (int g = 0; g < 4; ++g) {
      const int c = bc + g * 16 + (lane & 15);
      short4v p;
      #pragma unroll
      for (int i = 0; i < 4; ++i) p[i] = (short)f2b(acc[f][g][i]);
      *(short4v*)(out + (size_t)c * 256 + kb) = p;     // [c][k] layout, contiguous 8B
    }
  }
}

// ---- k_mred: grid 256. b=x&7, linear 16-seg bf16 reduce, *invN -> Mt[b][c][k].
__global__ __launch_bounds__(256) void k_mred(const short* __restrict__ Macc, short* __restrict__ Mt) {
  const int x = blockIdx.x, tid = threadIdx.x;
  const int b = x & 7, chunk = x >> 3;
  const int i0 = chunk * 2048 + tid * 8;
  float s[8] = {};
  #pragma unroll
  for (int seg = 0; seg < 16; ++seg) {
    short8v v = *(const short8v*)(Macc + (size_t)(seg * 8 + b) * 65536 + i0);
    #pragma unroll
    for (int q = 0; q < 8; ++q) s[q] += b2f(v[q]);
  }
  const float invN = 1.0f / (float)NVAL;
  short8v o;
  #pragma unroll
  for (int q = 0; q < 8; ++q) o[q] = (short)f2b(s[q] * invN);
  *(short8v*)(Mt + (size_t)b * 65536 + i0) = o;
}

// ---- k_apply: grid 512. b=x&7, t=x>>3 (0..63): 64n x 128c tile (4 waves, each
//      64x32). Residual in BF16: res = b2f(Zxin) + acc. Intermediate layers
//      write bf16 staging; final layer writes fp32 d_out.
__global__ __launch_bounds__(256) void k_apply(const short* __restrict__ Zxin, const short* __restrict__ Mt,
                                               const float* __restrict__ mcol,
                                               short* __restrict__ Zxout, short* __restrict__ Zxt_out,
                                               float* __restrict__ zlab, float* __restrict__ zlabtrue,
                                               float* __restrict__ dout, int wnext) {
  __shared__ short ldsT[128][72];
  const int tid = threadIdx.x, lane = tid & 63, wid = tid >> 6;
  const int x = blockIdx.x;
  const int b = x & 7, t = x >> 3;
  const int n0 = (t >> 1) * 64, c0 = (t & 1) * 128;
  const int bc = c0 + wid * 32;
  const short* A = Zxin + (size_t)b * NTOK * DD;
  const short* B = Mt + (size_t)b * 65536;
  const bool gemv = ((t & 1) == 0 && wid == 0);
  f32x4 acc[4][2];
  #pragma unroll
  for (int f = 0; f < 4; ++f) for (int g = 0; g < 2; ++g) for (int i = 0; i < 4; ++i) acc[f][g][i] = 0.f;
  float s[4] = {0.f, 0.f, 0.f, 0.f};
  #pragma unroll 2
  for (int kk = 0; kk < 256; kk += 32) {
    const int kc = kk + ((lane >> 4) << 3);
    short8v av[4], bv[2];
    #pragma unroll
    for (int f = 0; f < 4; ++f)
      av[f] = *(const short8v*)(A + (size_t)(n0 + f * 16 + (lane & 15)) * DD + kc);
    #pragma unroll
    for (int g = 0; g < 2; ++g)
      bv[g] = *(const short8v*)(B + (size_t)(bc + g * 16 + (lane & 15)) * 256 + kc);
    if (gemv) {
      const float* mp = mcol + b * 256 + kc;
      f32x4 m0 = *(const f32x4*)mp, m1 = *(const f32x4*)(mp + 4);
      #pragma unroll
      for (int f = 0; f < 4; ++f) {
        #pragma unroll
        for (int q = 0; q < 4; ++q) {
          s[f] += b2f(av[f][q]) * m0[q];
          s[f] += b2f(av[f][4 + q]) * m1[q];
        }
      }
    }
    #pragma unroll
    for (int f = 0; f < 4; ++f)
      #pragma unroll
      for (int g = 0; g < 2; ++g)
        acc[f][g] = __builtin_amdgcn_mfma_f32_16x16x32_bf16(av[f], bv[g], acc[f][g], 0, 0, 0);
  }
  #pragma unroll
  for (int f = 0; f < 4; ++f) {
    const int nb = n0 + f * 16 + ((lane >> 4) << 2);
    #pragma unroll
    for (int g = 0; g < 2; ++g) {
      const int c = bc + g * 16 + (lane & 15);
      #pragma unroll
      for (int i = 0; i < 4; ++i) {
        const size_t ridx = ((size_t)b * NTOK + nb + i) * DD + c;
        float nv = b2f(Zxin[ridx]) + acc[f][g][i];
        if (wnext) {
          unsigned short bvv = f2b(nv);
          Zxout[ridx] = (short)bvv;
          ldsT[c - c0][nb - n0 + i] = (nb + i == NVAL) ? (short)0 : (short)bvv;
        } else {
          dout[((size_t)b * NTOK + nb + i) * NCH + c] = nv;
        }
      }
    }
  }
  if (gemv) {
    #pragma unroll
    for (int f = 0; f < 4; ++f) {
      float tt = s[f];
      tt += __shfl_xor(tt, 16);
      tt += __shfl_xor(tt, 32);
      if ((lane >> 4) == 0) {
        int n = n0 + f * 16 + (lane & 15);
        float nv = zlabtrue[b * NTOK + n] + tt;
        if (wnext) {
          zlabtrue[b * NTOK + n] = nv;
          zlab[b * NTOK + n] = (n == NVAL) ? 0.f : nv;
        } else {
          dout[((size_t)b * NTOK + n) * NCH + DD] = nv;
        }
      }
    }
  }
  if (wnext) {
    __syncthreads();
    #pragma unroll
    for (int u = 0; u < 4; ++u) {
      const int e = tid + u * 256;
      const int cr = e >> 3, ch = e & 7;
      short8v v = *(const short8v*)&ldsT[cr][ch * 8];
      *(short8v*)(Zxt_out + ((size_t)b * DD + c0 + cr) * NTOK + n0 + ch * 8) = v;
    }
  }
}

// =====================================================================================
extern "C" void kernel_launch(void* const* d_in, const int* in_sizes, int n_in,
                              void* d_out, int out_size, void* d_ws, size_t ws_size,
                              hipStream_t stream) {
  const float* Zin      = (const float*)d_in[0];
  const float* allparam = (const float*)d_in[1];
  float* Z = (float*)d_out;

  // ws layout (bytes)
  const size_t o_zx0  = 0;                         // bf16 [8][2048][256]    8,388,608 (ping)
  const size_t o_zx1  = o_zx0  + 8388608;          // bf16                   8,388,608 (pong)
  const size_t o_zxt  = o_zx1  + 8388608;          // bf16 [8][256][2048]    8,388,608
  const size_t o_acc  = o_zxt  + 8388608;          // bf16 [16][8][256][256] 16,777,216 (Gacc/Macc alias)
  const size_t o_gbf  = o_acc  + 16777216;         // bf16 [8][256][256]     1,048,576
  const size_t o_vt   = o_gbf  + 1048576;          // bf16 [8][256][2048]    8,388,608 (Vt3)
  const size_t o_mt   = o_vt   + 8388608;          // bf16 [8][256][256]     1,048,576
  const size_t o_pbf  = o_mt   + 1048576;          // bf16 [4][8][256][256]  4,194,304
  const size_t o_qc2  = o_pbf  + 4194304;          // bf16 [4][256][2048]    4,194,304 (Qcat2)
  const size_t o_qsum = o_qc2  + 4194304;          // f32  [4][256][256]     1,048,576
  const size_t o_gca  = o_qsum + 1048576;          // f32  [8][8][256]       65,536 (gcolacc)
  const size_t o_gcol = o_gca  + 65536;            // f32  [8][256]          8,192
  const size_t o_mcol = o_gcol + 8192;             // f32  [8][256]          8,192
  const size_t o_zlab = o_mcol + 8192;             // f32  [8][2048]         65,536
  const size_t o_zlt  = o_zlab + 65536;            // f32  [8][2048]         65,536 (zlabtrue)
  const size_t NEED   = o_zlt  + 65536;
  if (ws_size < NEED) return;                      // harness ws is larger; never hit

  char* wsb = (char*)d_ws;
  short* Zx[2]   = { (short*)(wsb + o_zx0), (short*)(wsb + o_zx1) };
  short* Zxt     = (short*)(wsb + o_zxt);
  short* Acc     = (short*)(wsb + o_acc);
  short* Gbf     = (short*)(wsb + o_gbf);
  short* Vt3     = (short*)(wsb + o_vt);
  short* Mt      = (short*)(wsb + o_mt);
  short* Pbf     = (short*)(wsb + o_pbf);
  short* Qcat2   = (short*)(wsb + o_qc2);
  float* QsumT   = (float*)(wsb + o_qsum);
  float* gcolacc = (float*)(wsb + o_gca);
  float* gcol    = (float*)(wsb + o_gcol);
  float* mcol    = (float*)(wsb + o_mcol);
  float* zlab    = (float*)(wsb + o_zlab);
  float* zlabtrue= (float*)(wsb + o_zlt);

  k_init<<<dim3(3136), dim3(256), 0, stream>>>(Zin, allparam, Pbf, Qcat2, QsumT,
                                               Zx[0], Zxt, zlab, zlabtrue);

  for (int layer = 0; layer < NL; ++layer) {
    const int cur = layer & 1;
    const int wnext = (layer < NL - 1) ? 1 : 0;
    k_gram<<<dim3(448), dim3(256), 0, stream>>>(Zxt, Zx[cur], zlab, Acc, gcolacc);
    k_gred<<<dim3(264), dim3(256), 0, stream>>>(Acc, gcolacc, Gbf, gcol);
    k_pv<<<dim3(520), dim3(256), 0, stream>>>(Gbf, Pbf, QsumT, gcol, Vt3, mcol, layer);
    k_qm<<<dim3(512), dim3(256), 0, stream>>>(Vt3, Qcat2, Acc, layer);
    k_mred<<<dim3(256), dim3(256), 0, stream>>>(Acc, Mt);
    k_apply<<<dim3(512), dim3(256), 0, stream>>>(Zx[cur], Mt, mcol,
                                                 Zx[cur ^ 1], Zxt, zlab, zlabtrue,
                                                 Z, wnext);
  }
}

// Round 14
// 345.739 us; speedup vs baseline: 1.3463x; 1.0006x over previous
//
#include <hip/hip_runtime.h>

// MetaTransformer collapse: per layer,
//   G[b]  = Zx[b,:2047]^T Zx[b,:2047]   (256x256, symmetric)   gcol = Zx^T zlab
//   V     = G Pcat^T  (256 x 2048 stacked heads);  M = Qcat2 (Vt3)^T  (K=2048)
//   mcol  = (1/N) QsumT^T gcol
//   Z[b] += Zx[b] M[b]  (+ label-col GEMV with mcol)
// Residual carried in BF16 (Zx ping-pong) + fp32 zlabtrue; fp32 d_out written
// only in the final layer. bf16 transposed partials: gram split-K-16, qm
// split-K-8 (64kx128c tiles, K=256 dbuf). mm_t double-buffers the K-loop.
// XCD-aligned b = x&7 everywhere. 25 dispatches.

#define NL   4
#define NH   8
#define DD   256
#define NCH  257
#define NTOK 2048
#define NVAL 2047
#define NB   8

typedef short  short8v __attribute__((ext_vector_type(8)));
typedef short  short4v __attribute__((ext_vector_type(4)));
typedef float  f32x4   __attribute__((ext_vector_type(4)));

__device__ __forceinline__ unsigned short f2b(float x) {
  union { float f; unsigned u; } v; v.f = x;
  unsigned u = v.u + 0x7fffu + ((v.u >> 16) & 1u);
  return (unsigned short)(u >> 16);
}
__device__ __forceinline__ float b2f(short s) {
  union { unsigned u; float f; } v; v.u = ((unsigned)(unsigned short)s) << 16;
  return v.f;
}

// ---- MFMA tile, double-buffered K-loop: one wave computes (NF*16)x(NG*16).
// K range [k0,k1) must be a multiple of 64 (all call sites are).
template <int NF, int NG>
__device__ __forceinline__ void mm_t(const short* A, const short* B, int lda, int ldb,
                                     int ar, int bc, int k0, int k1, int lane,
                                     f32x4 (&acc)[NF][NG]) {
  const int kc = (lane >> 4) << 3;
  const int al = lane & 15;
  short8v a0[NF], b0[NG], a1[NF], b1[NG];
  #pragma unroll
  for (int f = 0; f < NF; ++f) a0[f] = *(const short8v*)(A + (size_t)(ar + f * 16 + al) * lda + k0 + kc);
  #pragma unroll
  for (int g = 0; g < NG; ++g) b0[g] = *(const short8v*)(B + (size_t)(bc + g * 16 + al) * ldb + k0 + kc);
  for (int kk = k0 + 32; kk < k1; kk += 64) {
    #pragma unroll
    for (int f = 0; f < NF; ++f) a1[f] = *(const short8v*)(A + (size_t)(ar + f * 16 + al) * lda + kk + kc);
    #pragma unroll
    for (int g = 0; g < NG; ++g) b1[g] = *(const short8v*)(B + (size_t)(bc + g * 16 + al) * ldb + kk + kc);
    #pragma unroll
    for (int f = 0; f < NF; ++f)
      #pragma unroll
      for (int g = 0; g < NG; ++g)
        acc[f][g] = __builtin_amdgcn_mfma_f32_16x16x32_bf16(a0[f], b0[g], acc[f][g], 0, 0, 0);
    if (kk + 32 < k1) {
      #pragma unroll
      for (int f = 0; f < NF; ++f) a0[f] = *(const short8v*)(A + (size_t)(ar + f * 16 + al) * lda + kk + 32 + kc);
      #pragma unroll
      for (int g = 0; g < NG; ++g) b0[g] = *(const short8v*)(B + (size_t)(bc + g * 16 + al) * ldb + kk + 32 + kc);
    }
    #pragma unroll
    for (int f = 0; f < NF; ++f)
      #pragma unroll
      for (int g = 0; g < NG; ++g)
        acc[f][g] = __builtin_amdgcn_mfma_f32_16x16x32_bf16(a1[f], b1[g], acc[f][g], 0, 0, 0);
  }
}

// ---- k_init: flat grid 3136.
//   [0,1024)     P cast -> Pbf
//   [1024,2048)  Q permute-cast -> Qcat2[l][k][j*256+t]
//   [2048,2112)  QsumT[l][t][k] = sum_j Q_j[k][t]  (fp32)
//   [2112,3136)  Zin -> Zxbf (natural bf16), Zxt (transposed, m=2047 zeroed),
//                zlab (zeroed @ NVAL) + zlabtrue (exact). float4 Zin loads.
__global__ __launch_bounds__(256) void k_init(const float* __restrict__ Zin,
                                              const float* __restrict__ ap,
                                              short* __restrict__ Pbf, short* __restrict__ Qcat2,
                                              float* __restrict__ QsumT,
                                              short* __restrict__ Zxbf, short* __restrict__ Zxt,
                                              float* __restrict__ zlab, float* __restrict__ zlabtrue) {
  __shared__ float lds[64][65];
  const int bx = blockIdx.x, tid = threadIdx.x;
  if (bx < 1024) {
    const f32x4* src = (const f32x4*)ap;
    int q0 = (bx * 256 + tid) * 2;
    #pragma unroll
    for (int u = 0; u < 2; ++u) {
      int q = q0 + u, lj = q >> 14, rc4 = q & 16383;
      f32x4 v = src[(size_t)(lj * 2) * 16384 + rc4];
      short4v o;
      #pragma unroll
      for (int i = 0; i < 4; ++i) o[i] = (short)f2b(v[i]);
      ((short4v*)Pbf)[(size_t)lj * 16384 + rc4] = o;
    }
    return;
  }
  if (bx < 2048) {
    int idx = bx - 1024;
    int l = idx >> 8, k = idx & 255;
    int j = tid >> 5, t0 = (tid & 31) * 8;
    const float* s = ap + (size_t)((l * 8 + j) * 2 + 1) * 65536 + (size_t)k * 256 + t0;
    f32x4 a = *(const f32x4*)s, bq = *(const f32x4*)(s + 4);
    short8v o;
    #pragma unroll
    for (int i = 0; i < 4; ++i) { o[i] = (short)f2b(a[i]); o[4 + i] = (short)f2b(bq[i]); }
    *(short8v*)(Qcat2 + (size_t)(l * 256 + k) * 2048 + j * 256 + t0) = o;
    return;
  }
  if (bx < 2112) {
    int qb = bx - 2048;
    int l = qb >> 4, xx = qb & 15;
    int k0 = (xx >> 2) * 64, t0 = (xx & 3) * 64;
    int c = tid & 63, r = tid >> 6;
    #pragma unroll
    for (int i = 0; i < 16; ++i) {
      int k = r + i * 4;
      float s = 0.f;
      #pragma unroll
      for (int j = 0; j < 8; ++j)
        s += ap[(size_t)((l * 8 + j) * 2 + 1) * 65536 + (size_t)(k0 + k) * 256 + (t0 + c)];
      lds[k][c] = s;
    }
    __syncthreads();
    #pragma unroll
    for (int i = 0; i < 16; ++i) {
      int tl = r + i * 4;
      QsumT[(size_t)l * 65536 + (size_t)(t0 + tl) * 256 + (k0 + c)] = lds[c][tl];
    }
    return;
  }
  int tb = bx - 2112;
  int x = tb & 3, y = (tb >> 2) & 31, b = tb >> 7;
  int k0 = x * 64, m0 = y * 64;
  const int c4 = (tid & 15) * 4, rr = tid >> 4;
  #pragma unroll
  for (int i = 0; i < 4; ++i) {
    int mrow = rr + i * 16, m = m0 + mrow;
    f32x4 v = *(const f32x4*)(Zin + ((size_t)b * NTOK + m) * NCH + k0 + c4);
    short4v o;
    #pragma unroll
    for (int q = 0; q < 4; ++q) { lds[mrow][c4 + q] = v[q]; o[q] = (short)f2b(v[q]); }
    *(short4v*)(Zxbf + ((size_t)b * NTOK + m) * DD + k0 + c4) = o;
  }
  if (x == 0 && tid < 64) {
    int m = m0 + tid;
    float lv = Zin[((size_t)b * NTOK + m) * NCH + DD];
    zlabtrue[b * NTOK + m] = lv;
    zlab[b * NTOK + m] = (m == NVAL) ? 0.f : lv;
  }
  __syncthreads();
  const int mt = tid & 15, kg = tid >> 4;
  #pragma unroll
  for (int i = 0; i < 4; ++i) {
    int krow = kg * 4 + i;
    int m4 = mt * 4;
    short4v o;
    #pragma unroll
    for (int q = 0; q < 4; ++q) {
      float v = lds[m4 + q][krow];
      o[q] = (m0 + m4 + q == NVAL) ? (short)0 : (short)f2b(v);
    }
    *(short4v*)(Zxt + ((size_t)b * DD + k0 + krow) * NTOK + m0 + m4) = o;
  }
}

// ---- k_gram: grid 448. x<384: b=x&7, r=x>>3 (0..47): q=r%3 quadrant, seg=r/3
//      (K=128 window). q=0: (0,0); q=1: (1,1); q=2: (0,1) + mirror into (1,0).
//      bf16 partials stored TRANSPOSED (col-major; G symmetric).
//      x>=384: gcol partials over 256-m segment via Zxbf.
__global__ __launch_bounds__(256) void k_gram(const short* __restrict__ Zxt,
                                              const short* __restrict__ Zxbf,
                                              const float* __restrict__ zlab,
                                              short* __restrict__ Gacc,
                                              float* __restrict__ gcolacc) {
  __shared__ float zl[256];
  const int x = blockIdx.x, tid = threadIdx.x;
  if (x >= 384) {
    const int idx = x - 384, b = idx & 7, seg = idx >> 3;
    zl[tid] = zlab[b * NTOK + seg * 256 + tid];
    __syncthreads();
    const short* base = Zxbf + ((size_t)b * NTOK + seg * 256) * DD + tid;
    float s = 0.f;
    #pragma unroll 8
    for (int m = 0; m < 256; ++m) s += b2f(base[(size_t)m * DD]) * zl[m];
    gcolacc[(seg * 8 + b) * 256 + tid] = s;
    return;
  }
  const int lane = tid & 63, wid = tid >> 6;
  const int b = x & 7, r = x >> 3;
  const int q = r % 3, seg = r / 3;
  const int r0 = (q == 1) ? 128 : 0;
  const int c0 = (q == 0) ? 0 : 128;
  const int ar = r0 + (wid >> 1) * 64, bc = c0 + (wid & 1) * 64;
  const short* A = Zxt + (size_t)b * DD * NTOK;
  f32x4 acc[4][4];
  #pragma unroll
  for (int f = 0; f < 4; ++f) for (int g = 0; g < 4; ++g) for (int i = 0; i < 4; ++i) acc[f][g][i] = 0.f;
  mm_t<4, 4>(A, A, NTOK, NTOK, ar, bc, seg * 128, seg * 128 + 128, lane, acc);
  short* out = Gacc + (size_t)(seg * 8 + b) * 65536;
  #pragma unroll
  for (int f = 0; f < 4; ++f) {
    const int rb = ar + f * 16 + ((lane >> 4) << 2);
    #pragma unroll
    for (int g = 0; g < 4; ++g) {
      const int col = bc + g * 16 + (lane & 15);
      short4v p;
      #pragma unroll
      for (int i = 0; i < 4; ++i) p[i] = (short)f2b(acc[f][g][i]);
      *(short4v*)(out + (size_t)col * 256 + rb) = p;     // transposed, contiguous 8B
      if (q == 2) {
        #pragma unroll
        for (int i = 0; i < 4; ++i)
          out[(size_t)(rb + i) * 256 + col] = p[i];      // mirror into (1,0)
      }
    }
  }
}

// ---- k_gred: grid 264. x<256: b=x&7, linear 16-seg bf16 reduce -> Gbf (16B ld/st).
//      x>=256: gcol 8-seg reduce.
__global__ __launch_bounds__(256) void k_gred(const short* __restrict__ Gacc,
                                              const float* __restrict__ gcolacc,
                                              short* __restrict__ Gbf, float* __restrict__ gcol) {
  const int x = blockIdx.x, tid = threadIdx.x;
  if (x >= 256) {
    const int b = x - 256;
    float s = 0.f;
    #pragma unroll
    for (int seg = 0; seg < 8; ++seg) s += gcolacc[(seg * 8 + b) * 256 + tid];
    gcol[b * 256 + tid] = s;
    return;
  }
  const int b = x & 7, chunk = x >> 3;
  const int i0 = chunk * 2048 + tid * 8;
  float s[8] = {};
  #pragma unroll
  for (int seg = 0; seg < 16; ++seg) {
    short8v v = *(const short8v*)(Gacc + (size_t)(seg * 8 + b) * 65536 + i0);
    #pragma unroll
    for (int q = 0; q < 8; ++q) s[q] += b2f(v[q]);
  }
  short8v o;
  #pragma unroll
  for (int q = 0; q < 8; ++q) o[q] = (short)f2b(s[q]);
  *(short8v*)(Gbf + (size_t)b * 65536 + i0) = o;
}

// ---- k_pv: grid 520. x<512: b=x&7, t=x>>3 (0..63): 64t x 128jc tile of
//      V = G Pcat^T (4 waves, each 64x32); write Vt3[b][c][j*256+t].
//      x>=512: mcol = invN * QsumT gcol (coalesced).
__global__ __launch_bounds__(256) void k_pv(const short* __restrict__ Gbf, const short* __restrict__ Pbf,
                                            const float* __restrict__ QsumT, const float* __restrict__ gcol,
                                            short* __restrict__ Vt3, float* __restrict__ mcol, int layer) {
  __shared__ float gs[256];
  const int x = blockIdx.x, tid = threadIdx.x;
  if (x >= 512) {
    const int b = x - 512;
    gs[tid] = gcol[b * 256 + tid];
    __syncthreads();
    float s = 0.f;
    for (int t = 0; t < 256; ++t) s += QsumT[(size_t)layer * 65536 + (size_t)t * 256 + tid] * gs[t];
    mcol[b * 256 + tid] = s * (1.0f / (float)NVAL);
    return;
  }
  const int lane = tid & 63, wid = tid >> 6;
  const int b = x & 7, t = x >> 3;
  const int r0 = (t & 3) * 64, jc0 = (t >> 2) * 128;
  const int bc = jc0 + wid * 32;
  const short* A = Gbf + (size_t)b * 65536;
  const short* B = Pbf + (size_t)layer * 8 * 65536;
  f32x4 acc[4][2];
  #pragma unroll
  for (int f = 0; f < 4; ++f) for (int g = 0; g < 2; ++g) for (int i = 0; i < 4; ++i) acc[f][g][i] = 0.f;
  mm_t<4, 2>(A, B, 256, 256, r0, bc, 0, 256, lane, acc);
  short* out = Vt3 + (size_t)b * 524288;
  #pragma unroll
  for (int f = 0; f < 4; ++f) {
    const int tt0 = r0 + f * 16 + ((lane >> 4) << 2);
    #pragma unroll
    for (int g = 0; g < 2; ++g) {
      const int jc = bc + g * 16 + (lane & 15);
      const int j = jc >> 8, c = jc & 255;
      short4v p;
      #pragma unroll
      for (int i = 0; i < 4; ++i) p[i] = (short)f2b(acc[f][g][i]);
      *(short4v*)(out + (size_t)c * 2048 + j * 256 + tt0) = p;
    }
  }
}

// ---- k_qm: grid 512. b=x&7, tile=(x>>3)&7 (64k x 128c of M), seg=x>>6 (8 segs,
//      K=256 of jt). A'=Qcat2[l] rows k, B'=Vt3[b] rows c -> out[k][c]; bf16
//      partial stored TRANSPOSED => Macc[seg][b][c*256+k] (contiguous short4).
__global__ __launch_bounds__(256) void k_qm(const short* __restrict__ Vt3, const short* __restrict__ Qcat2,
                                            short* __restrict__ Macc, int layer) {
  const int x = blockIdx.x, tid = threadIdx.x;
  const int lane = tid & 63, wid = tid >> 6;
  const int b = x & 7, t = (x >> 3) & 7, seg = x >> 6;
  const int k0 = (t & 3) * 64, c0 = (t >> 2) * 128;
  const int bc = c0 + wid * 32;
  const short* A = Qcat2 + (size_t)layer * 524288;
  const short* B = Vt3 + (size_t)b * 524288;
  f32x4 acc[4][2];
  #pragma unroll
  for (int f = 0; f < 4; ++f) for (int g = 0; g < 2; ++g) for (int i = 0; i < 4; ++i) acc[f][g][i] = 0.f;
  mm_t<4, 2>(A, B, 2048, 2048, k0, bc, seg * 256, seg * 256 + 256, lane, acc);
  short* out = Macc + (size_t)(seg * 8 + b) * 65536;
  #pragma unroll
  for (int f = 0; f < 4; ++f) {
    const int kb = k0 + f * 16 + ((lane >> 4) << 2);
    #pragma unroll
    for (int g = 0; g < 2; ++g) {
      const int c = bc + g * 16 + (lane & 15);
      short4v p;
      #pragma unroll
      for (int i = 0; i < 4; ++i) p[i] = (short)f2b(acc[f][g][i]);
      *(short4v*)(out + (size_t)c * 256 + kb) = p;     // [c][k] layout, contiguous 8B
    }
  }
}

// ---- k_mred: grid 256. b=x&7, linear 8-seg bf16 reduce, *invN -> Mt[b][c][k].
__global__ __launch_bounds__(256) void k_mred(const short* __restrict__ Macc, short* __restrict__ Mt) {
  const int x = blockIdx.x, tid = threadIdx.x;
  const int b = x & 7, chunk = x >> 3;
  const int i0 = chunk * 2048 + tid * 8;
  float s[8] = {};
  #pragma unroll
  for (int seg = 0; seg < 8; ++seg) {
    short8v v = *(const short8v*)(Macc + (size_t)(seg * 8 + b) * 65536 + i0);
    #pragma unroll
    for (int q = 0; q < 8; ++q) s[q] += b2f(v[q]);
  }
  const float invN = 1.0f / (float)NVAL;
  short8v o;
  #pragma unroll
  for (int q = 0; q < 8; ++q) o[q] = (short)f2b(s[q] * invN);
  *(short8v*)(Mt + (size_t)b * 65536 + i0) = o;
}

// ---- k_apply: grid 512. b=x&7, t=x>>3 (0..63): 64n x 128c tile (4 waves, each
//      64x32). Residual in BF16: res = b2f(Zxin) + acc. Intermediate layers
//      write bf16 staging; final layer writes fp32 d_out.
__global__ __launch_bounds__(256) void k_apply(const short* __restrict__ Zxin, const short* __restrict__ Mt,
                                               const float* __restrict__ mcol,
                                               short* __restrict__ Zxout, short* __restrict__ Zxt_out,
                                               float* __restrict__ zlab, float* __restrict__ zlabtrue,
                                               float* __restrict__ dout, int wnext) {
  __shared__ short ldsT[128][72];
  const int tid = threadIdx.x, lane = tid & 63, wid = tid >> 6;
  const int x = blockIdx.x;
  const int b = x & 7, t = x >> 3;
  const int n0 = (t >> 1) * 64, c0 = (t & 1) * 128;
  const int bc = c0 + wid * 32;
  const short* A = Zxin + (size_t)b * NTOK * DD;
  const short* B = Mt + (size_t)b * 65536;
  const bool gemv = ((t & 1) == 0 && wid == 0);
  f32x4 acc[4][2];
  #pragma unroll
  for (int f = 0; f < 4; ++f) for (int g = 0; g < 2; ++g) for (int i = 0; i < 4; ++i) acc[f][g][i] = 0.f;
  float s[4] = {0.f, 0.f, 0.f, 0.f};
  #pragma unroll 2
  for (int kk = 0; kk < 256; kk += 32) {
    const int kc = kk + ((lane >> 4) << 3);
    short8v av[4], bv[2];
    #pragma unroll
    for (int f = 0; f < 4; ++f)
      av[f] = *(const short8v*)(A + (size_t)(n0 + f * 16 + (lane & 15)) * DD + kc);
    #pragma unroll
    for (int g = 0; g < 2; ++g)
      bv[g] = *(const short8v*)(B + (size_t)(bc + g * 16 + (lane & 15)) * 256 + kc);
    if (gemv) {
      const float* mp = mcol + b * 256 + kc;
      f32x4 m0 = *(const f32x4*)mp, m1 = *(const f32x4*)(mp + 4);
      #pragma unroll
      for (int f = 0; f < 4; ++f) {
        #pragma unroll
        for (int q = 0; q < 4; ++q) {
          s[f] += b2f(av[f][q]) * m0[q];
          s[f] += b2f(av[f][4 + q]) * m1[q];
        }
      }
    }
    #pragma unroll
    for (int f = 0; f < 4; ++f)
      #pragma unroll
      for (int g = 0; g < 2; ++g)
        acc[f][g] = __builtin_amdgcn_mfma_f32_16x16x32_bf16(av[f], bv[g], acc[f][g], 0, 0, 0);
  }
  #pragma unroll
  for (int f = 0; f < 4; ++f) {
    const int nb = n0 + f * 16 + ((lane >> 4) << 2);
    #pragma unroll
    for (int g = 0; g < 2; ++g) {
      const int c = bc + g * 16 + (lane & 15);
      #pragma unroll
      for (int i = 0; i < 4; ++i) {
        const size_t ridx = ((size_t)b * NTOK + nb + i) * DD + c;
        float nv = b2f(Zxin[ridx]) + acc[f][g][i];
        if (wnext) {
          unsigned short bvv = f2b(nv);
          Zxout[ridx] = (short)bvv;
          ldsT[c - c0][nb - n0 + i] = (nb + i == NVAL) ? (short)0 : (short)bvv;
        } else {
          dout[((size_t)b * NTOK + nb + i) * NCH + c] = nv;
        }
      }
    }
  }
  if (gemv) {
    #pragma unroll
    for (int f = 0; f < 4; ++f) {
      float tt = s[f];
      tt += __shfl_xor(tt, 16);
      tt += __shfl_xor(tt, 32);
      if ((lane >> 4) == 0) {
        int n = n0 + f * 16 + (lane & 15);
        float nv = zlabtrue[b * NTOK + n] + tt;
        if (wnext) {
          zlabtrue[b * NTOK + n] = nv;
          zlab[b * NTOK + n] = (n == NVAL) ? 0.f : nv;
        } else {
          dout[((size_t)b * NTOK + n) * NCH + DD] = nv;
        }
      }
    }
  }
  if (wnext) {
    __syncthreads();
    #pragma unroll
    for (int u = 0; u < 4; ++u) {
      const int e = tid + u * 256;
      const int cr = e >> 3, ch = e & 7;
      short8v v = *(const short8v*)&ldsT[cr][ch * 8];
      *(short8v*)(Zxt_out + ((size_t)b * DD + c0 + cr) * NTOK + n0 + ch * 8) = v;
    }
  }
}

// =====================================================================================
extern "C" void kernel_launch(void* const* d_in, const int* in_sizes, int n_in,
                              void* d_out, int out_size, void* d_ws, size_t ws_size,
                              hipStream_t stream) {
  const float* Zin      = (const float*)d_in[0];
  const float* allparam = (const float*)d_in[1];
  float* Z = (float*)d_out;

  // ws layout (bytes)
  const size_t o_zx0  = 0;                         // bf16 [8][2048][256]    8,388,608 (ping)
  const size_t o_zx1  = o_zx0  + 8388608;          // bf16                   8,388,608 (pong)
  const size_t o_zxt  = o_zx1  + 8388608;          // bf16 [8][256][2048]    8,388,608
  const size_t o_acc  = o_zxt  + 8388608;          // bf16 [16][8][256][256] 16,777,216 (Gacc/Macc alias)
  const size_t o_gbf  = o_acc  + 16777216;         // bf16 [8][256][256]     1,048,576
  const size_t o_vt   = o_gbf  + 1048576;          // bf16 [8][256][2048]    8,388,608 (Vt3)
  const size_t o_mt   = o_vt   + 8388608;          // bf16 [8][256][256]     1,048,576
  const size_t o_pbf  = o_mt   + 1048576;          // bf16 [4][8][256][256]  4,194,304
  const size_t o_qc2  = o_pbf  + 4194304;          // bf16 [4][256][2048]    4,194,304 (Qcat2)
  const size_t o_qsum = o_qc2  + 4194304;          // f32  [4][256][256]     1,048,576
  const size_t o_gca  = o_qsum + 1048576;          // f32  [8][8][256]       65,536 (gcolacc)
  const size_t o_gcol = o_gca  + 65536;            // f32  [8][256]          8,192
  const size_t o_mcol = o_gcol + 8192;             // f32  [8][256]          8,192
  const size_t o_zlab = o_mcol + 8192;             // f32  [8][2048]         65,536
  const size_t o_zlt  = o_zlab + 65536;            // f32  [8][2048]         65,536 (zlabtrue)
  const size_t NEED   = o_zlt  + 65536;
  if (ws_size < NEED) return;                      // harness ws is larger; never hit

  char* wsb = (char*)d_ws;
  short* Zx[2]   = { (short*)(wsb + o_zx0), (short*)(wsb + o_zx1) };
  short* Zxt     = (short*)(wsb + o_zxt);
  short* Acc     = (short*)(wsb + o_acc);
  short* Gbf     = (short*)(wsb + o_gbf);
  short* Vt3     = (short*)(wsb + o_vt);
  short* Mt      = (short*)(wsb + o_mt);
  short* Pbf     = (short*)(wsb + o_pbf);
  short* Qcat2   = (short*)(wsb + o_qc2);
  float* QsumT   = (float*)(wsb + o_qsum);
  float* gcolacc = (float*)(wsb + o_gca);
  float* gcol    = (float*)(wsb + o_gcol);
  float* mcol    = (float*)(wsb + o_mcol);
  float* zlab    = (float*)(wsb + o_zlab);
  float* zlabtrue= (float*)(wsb + o_zlt);

  k_init<<<dim3(3136), dim3(256), 0, stream>>>(Zin, allparam, Pbf, Qcat2, QsumT,
                                               Zx[0], Zxt, zlab, zlabtrue);

  for (int layer = 0; layer < NL; ++layer) {
    const int cur = layer & 1;
    const int wnext = (layer < NL - 1) ? 1 : 0;
    k_gram<<<dim3(448), dim3(256), 0, stream>>>(Zxt, Zx[cur], zlab, Acc, gcolacc);
    k_gred<<<dim3(264), dim3(256), 0, stream>>>(Acc, gcolacc, Gbf, gcol);
    k_pv<<<dim3(520), dim3(256), 0, stream>>>(Gbf, Pbf, QsumT, gcol, Vt3, mcol, layer);
    k_qm<<<dim3(512), dim3(256), 0, stream>>>(Vt3, Qcat2, Acc, layer);
    k_mred<<<dim3(256), dim3(256), 0, stream>>>(Acc, Mt);
    k_apply<<<dim3(512), dim3(256), 0, stream>>>(Zx[cur], Mt, mcol,
                                                 Zx[cur ^ 1], Zxt, zlab, zlabtrue,
                                                 Z, wnext);
  }
}